// Round 12
// baseline (330.505 us; speedup 1.0000x reference)
//
#include <hip/hip_runtime.h>
#include <hip/hip_bf16.h>

#define NN 100000
#define EE 1600000
#define ETOT (EE + NN)          // 1,700,000 edges incl. self-loops
#define IND 32
#define HIDD 64
#define NHEADS 4
#define OUTD 32
#define HID2D 32

#define BSH 8                   // 256 nodes per bucket
#define NBUCK 391               // ceil(NN / 256)
#define CAP 5120                // max edges per bucket (mean ~4348)
#define EPB 2048                // edges per bin block
#define NBBIN ((ETOT + EPB - 1) / EPB)   // 831
#define NBLIN1 (NN / 8)                  // 12500

typedef unsigned int uint;

__device__ __forceinline__ uint pack2(float a, float b) {
  uint lo = (uint)__bfloat16_as_ushort(__float2bfloat16(a));
  uint hi = (uint)__bfloat16_as_ushort(__float2bfloat16(b));
  return (hi << 16) | lo;
}
__device__ __forceinline__ float lo2f(uint w) { return __uint_as_float(w << 16); }
__device__ __forceinline__ float hi2f(uint w) { return __uint_as_float(w & 0xFFFF0000u); }

// ---------- merged: edge binning (blocks 0..NBBIN-1) + lin1 (rest) ----------
__global__ __launch_bounds__(256) void k_pre(
    const int* __restrict__ ei, int* __restrict__ bcur, int* __restrict__ bins,
    const float* __restrict__ x, const float* __restrict__ W1,
    const float* __restrict__ atsrc, const float* __restrict__ atdst,
    uint* __restrict__ h1u, float* __restrict__ as1, float* __restrict__ ad1) {
  __shared__ int cnt[NBUCK];
  __shared__ float Ws[IND * HIDD];
  __shared__ float xs[8 * IND];
  __shared__ float atS[HIDD], atD[HIDD];
  int t = threadIdx.x;
  if (blockIdx.x < NBBIN) {
    // ---- bin: bucket edges by dst>>8; record = (src<<8)|(dst&255) ----
    for (int i = t; i < NBUCK; i += 256) cnt[i] = 0;
    __syncthreads();
    int base = blockIdx.x * EPB;
    int recs[8], bks[8];
#pragma unroll
    for (int k = 0; k < 8; k++) {
      int i = base + k * 256 + t;
      recs[k] = -1; bks[k] = 0;
      if (i < ETOT) {
        int s, d;
        if (i < EE) { s = ei[i]; d = ei[EE + i]; } else { s = i - EE; d = s; }
        recs[k] = (s << BSH) | (d & ((1 << BSH) - 1));
        bks[k] = d >> BSH;
        atomicAdd(&cnt[bks[k]], 1);
      }
    }
    __syncthreads();
    for (int i = t; i < NBUCK; i += 256) cnt[i] = atomicAdd(&bcur[i], cnt[i]);
    __syncthreads();
#pragma unroll
    for (int k = 0; k < 8; k++) {
      if (recs[k] >= 0) {
        int pos = atomicAdd(&cnt[bks[k]], 1);
        bins[bks[k] * CAP + pos] = recs[k];
      }
    }
  } else {
    // ---- lin1: h1(bf16) = x @ W1 ; as1/ad1 f32 attention dots ----
    int bid = blockIdx.x - NBBIN;
    for (int i = t; i < IND * HIDD; i += 256) Ws[i] = W1[i];
    if (t < HIDD) { atS[t] = atsrc[t]; atD[t] = atdst[t]; }
    xs[t] = x[bid * 256 + t];
    __syncthreads();
    int nl = t >> 5, tl = t & 31;
    int node = bid * 8 + nl;
    int j0 = 2 * tl, j1 = j0 + 1;
    float a0 = 0.f, a1 = 0.f;
#pragma unroll
    for (int k = 0; k < IND; k++) {
      float xv = xs[nl * IND + k];
      a0 += xv * Ws[k * HIDD + j0];
      a1 += xv * Ws[k * HIDD + j1];
    }
    h1u[node * 32 + tl] = pack2(a0, a1);
    float ps = a0 * atS[j0] + a1 * atS[j1];
    float pd = a0 * atD[j0] + a1 * atD[j1];
#pragma unroll
    for (int off = 4; off >= 1; off >>= 1) {
      ps += __shfl_down(ps, off, 8);
      pd += __shfl_down(pd, off, 8);
    }
    if ((tl & 7) == 0) {
      as1[node * NHEADS + (tl >> 3)] = ps;
      ad1[node * NHEADS + (tl >> 3)] = pd;
    }
  }
}

// ---------- linear 2: h2(bf16) = hbn(f32) @ W2 ; as2/ad2 ----------
__global__ __launch_bounds__(256) void k_lin2(
    const float* __restrict__ hbn, const float* __restrict__ W2,
    const float* __restrict__ atsrc, const float* __restrict__ atdst,
    uint* __restrict__ h2u, float* __restrict__ as2, float* __restrict__ ad2) {
  __shared__ float Ws[HIDD * OUTD];
  __shared__ float xs[16 * HIDD];
  __shared__ float atS[OUTD], atD[OUTD];
  int t = threadIdx.x;
  for (int i = t; i < HIDD * OUTD; i += 256) Ws[i] = W2[i];
  if (t < OUTD) { atS[t] = atsrc[t]; atD[t] = atdst[t]; }
  for (int i = t; i < 16 * HIDD; i += 256) xs[i] = hbn[blockIdx.x * 16 * HIDD + i];
  __syncthreads();
  int nl = t >> 4, tl = t & 15;
  int node = blockIdx.x * 16 + nl;
  int j0 = 2 * tl, j1 = j0 + 1;
  float a0 = 0.f, a1 = 0.f;
#pragma unroll
  for (int k = 0; k < HIDD; k++) {
    float xv = xs[nl * HIDD + k];
    a0 += xv * Ws[k * OUTD + j0];
    a1 += xv * Ws[k * OUTD + j1];
  }
  h2u[node * 16 + tl] = pack2(a0, a1);
  float ps = a0 * atS[j0] + a1 * atS[j1];
  float pd = a0 * atD[j0] + a1 * atD[j1];
#pragma unroll
  for (int off = 8; off >= 1; off >>= 1) {
    ps += __shfl_down(ps, off, 16);
    pd += __shfl_down(pd, off, 16);
  }
  if (tl == 0) { as2[node] = ps; ad2[node] = pd; }
}

// ---------- per-bucket local CSR (391 blocks), inline 512-scan ----------
// srcs entries are stored PRE-SCALED by 8 (uint4/uint2 row offsets).
__global__ __launch_bounds__(256) void k_csr(const int* __restrict__ bcur,
                                             const int* __restrict__ bins,
                                             int* __restrict__ rowp,
                                             int* __restrict__ srcs) {
  __shared__ int lrec[CAP];          // 20KB
  __shared__ int sA[512], sB[512];
  __shared__ int ldeg[256];
  int b = blockIdx.x, t = threadIdx.x;
  if (b == 0) {                      // zero the 64-entry pad past ETOT
    if (t < 64) srcs[ETOT + t] = 0;
    if (t == 0) rowp[NN] = ETOT;
  }
  // inline exclusive scan of the NBUCK bucket counts
  sA[t] = (t < NBUCK) ? bcur[t] : 0;
  sA[t + 256] = (t + 256 < NBUCK) ? bcur[t + 256] : 0;
  __syncthreads();
  int* in = sA; int* out = sB;
  for (int off = 1; off < 512; off <<= 1) {
    for (int i = t; i < 512; i += 256)
      out[i] = in[i] + ((i >= off) ? in[i - off] : 0);
    __syncthreads();
    int* tmp = in; in = out; out = tmp;
  }
  int gb = (b == 0) ? 0 : in[b - 1];
  __syncthreads();
  int count = bcur[b]; if (count > CAP) count = CAP;
  ldeg[t] = 0;
  __syncthreads();
  for (int i = t; i < count; i += 256) {
    int r = bins[b * CAP + i];
    lrec[i] = r;
    atomicAdd(&ldeg[r & 255], 1);
  }
  __syncthreads();
  int dv = ldeg[t];
  sA[t] = dv;
  __syncthreads();
  in = sA; out = sB;
  for (int off = 1; off < 256; off <<= 1) {
    out[t] = in[t] + ((t >= off) ? in[t - off] : 0);
    __syncthreads();
    int* tmp = in; in = out; out = tmp;
  }
  int nb = b << BSH;
  int ex = in[t] - dv;               // exclusive scan
  if (nb + t < NN) rowp[nb + t] = gb + ex;
  ldeg[t] = ex;                      // reuse as scatter cursor
  __syncthreads();
  for (int i = t; i < count; i += 256) {
    int r = lrec[i];
    int pos = atomicAdd(&ldeg[r & 255], 1);
    srcs[gb + pos] = (r >> BSH) << 3;   // pre-scaled src*8
  }
}

// ---------- GAT1 aggregation + bias + BN1 + ReLU, DUAL-node waves ----------
// srcs pre-scaled by 8; pad past ETOT allows unclamped prefetch.
__global__ __launch_bounds__(256, 4) void k_agg1(
    const int* __restrict__ rowp, const int* __restrict__ srcs,
    const uint* __restrict__ h1u, const float* __restrict__ as1,
    const float* __restrict__ ad1, const float* __restrict__ b1,
    const float* __restrict__ g, const float* __restrict__ bb,
    const float* __restrict__ m, const float* __restrict__ v,
    float* __restrict__ hbn) {
  int t = threadIdx.x;
  int wid = t >> 6, lane = t & 63;
  int nA = blockIdx.x * 8 + wid * 2;
  int nB = nA + 1;
  int slot = lane >> 3;
  int fl = lane & 7;
  int hd = fl >> 1;
  int stA = rowp[nA], eA = rowp[nA + 1], eB = rowp[nB + 1];
  int stB = eA;
  float advA = ad1[nA * NHEADS + hd];
  float advB = ad1[nB * NHEADS + hd];
  const uint4* h14 = (const uint4*)h1u;
  float accA[8] = {0,0,0,0,0,0,0,0}, accB[8] = {0,0,0,0,0,0,0,0};
  float lA = 0.f, lB = 0.f;
  int pA = stA + slot, pB = stB + slot;
  int sA0 = srcs[pA];                 // pre-scaled s*8, pad-safe
  int sB0 = srcs[pB];
  uint4 wA = h14[sA0 + fl];
  uint4 wB = h14[sB0 + fl];
  float asA = as1[(sA0 >> 1) + hd];
  float asB = as1[(sB0 >> 1) + hd];
  int p1A = pA + 8, p1B = pB + 8;
  int sA1 = srcs[p1A];
  int sB1 = srcs[p1B];
  while (pA < eA || pB < eB) {
    uint4 wnA = h14[sA1 + fl];
    uint4 wnB = h14[sB1 + fl];
    float anA = as1[(sA1 >> 1) + hd];
    float anB = as1[(sB1 >> 1) + hd];
    int p2A = p1A + 8, p2B = p1B + 8;
    int sA2 = srcs[p2A < ETOT ? p2A : ETOT];
    int sB2 = srcs[p2B < ETOT ? p2B : ETOT];
    if (pA < eA) {
      float e = asA + advA;
      e = fmaxf(e, 0.2f * e);
      float ex = __expf(e);
      lA += ex;
      accA[0] += ex * lo2f(wA.x); accA[1] += ex * hi2f(wA.x);
      accA[2] += ex * lo2f(wA.y); accA[3] += ex * hi2f(wA.y);
      accA[4] += ex * lo2f(wA.z); accA[5] += ex * hi2f(wA.z);
      accA[6] += ex * lo2f(wA.w); accA[7] += ex * hi2f(wA.w);
    }
    if (pB < eB) {
      float e = asB + advB;
      e = fmaxf(e, 0.2f * e);
      float ex = __expf(e);
      lB += ex;
      accB[0] += ex * lo2f(wB.x); accB[1] += ex * hi2f(wB.x);
      accB[2] += ex * lo2f(wB.y); accB[3] += ex * hi2f(wB.y);
      accB[4] += ex * lo2f(wB.z); accB[5] += ex * hi2f(wB.z);
      accB[6] += ex * lo2f(wB.w); accB[7] += ex * hi2f(wB.w);
    }
    wA = wnA; wB = wnB; asA = anA; asB = anB;
    sA1 = sA2; sB1 = sB2;
    pA = p1A; pB = p1B; p1A = p2A; p1B = p2B;
  }
#pragma unroll
  for (int off = 8; off <= 32; off <<= 1) {
#pragma unroll
    for (int i = 0; i < 8; i++) {
      accA[i] += __shfl_xor(accA[i], off, 64);
      accB[i] += __shfl_xor(accB[i], off, 64);
    }
    lA += __shfl_xor(lA, off, 64);
    lB += __shfl_xor(lB, off, 64);
  }
  if (slot < 2) {
    int node = slot == 0 ? nA : nB;
    float lsum = slot == 0 ? lA : lB;
    float li = 1.f / (lsum + 1e-16f);
    int fb = fl * 8;
    float o[8];
#pragma unroll
    for (int i = 0; i < 8; i++) {
      int j = fb + i;
      float av = slot == 0 ? accA[i] : accB[i];
      float ov = av * li + b1[j];
      ov = (ov - m[j]) * rsqrtf(v[j] + 1e-5f) * g[j] + bb[j];
      o[i] = fmaxf(ov, 0.f);
    }
    float4* dst = (float4*)(hbn + node * HIDD + fb);
    dst[0] = make_float4(o[0], o[1], o[2], o[3]);
    dst[1] = make_float4(o[4], o[5], o[6], o[7]);
  }
}

// ---------- GAT2 aggregation + bias + BN2 + ReLU, DUAL-node waves ----------
__global__ __launch_bounds__(256, 4) void k_agg2(
    const int* __restrict__ rowp, const int* __restrict__ srcs,
    const uint* __restrict__ h2u, const float* __restrict__ as2,
    const float* __restrict__ ad2, const float* __restrict__ b2v,
    const float* __restrict__ g, const float* __restrict__ bb,
    const float* __restrict__ m, const float* __restrict__ v,
    float* __restrict__ out_emb) {
  int t = threadIdx.x;
  int wid = t >> 6, lane = t & 63;
  int nA = blockIdx.x * 8 + wid * 2;
  int nB = nA + 1;
  int slot = lane >> 3;
  int fl = lane & 7;         // feats fl*4..fl*4+3
  int stA = rowp[nA], eA = rowp[nA + 1], eB = rowp[nB + 1];
  int stB = eA;
  float advA = ad2[nA], advB = ad2[nB];
  const uint2* h22 = (const uint2*)h2u;
  float accA[4] = {0,0,0,0}, accB[4] = {0,0,0,0};
  float lA = 0.f, lB = 0.f;
  int pA = stA + slot, pB = stB + slot;
  int sA0 = srcs[pA];                 // pre-scaled s*8 (= uint2 row offset)
  int sB0 = srcs[pB];
  uint2 wA = h22[sA0 + fl];
  uint2 wB = h22[sB0 + fl];
  float asA = as2[sA0 >> 3], asB = as2[sB0 >> 3];
  int p1A = pA + 8, p1B = pB + 8;
  int sA1 = srcs[p1A];
  int sB1 = srcs[p1B];
  while (pA < eA || pB < eB) {
    uint2 wnA = h22[sA1 + fl];
    uint2 wnB = h22[sB1 + fl];
    float anA = as2[sA1 >> 3], anB = as2[sB1 >> 3];
    int p2A = p1A + 8, p2B = p1B + 8;
    int sA2 = srcs[p2A < ETOT ? p2A : ETOT];
    int sB2 = srcs[p2B < ETOT ? p2B : ETOT];
    if (pA < eA) {
      float e = asA + advA;
      e = fmaxf(e, 0.2f * e);
      float ex = __expf(e);
      lA += ex;
      accA[0] += ex * lo2f(wA.x); accA[1] += ex * hi2f(wA.x);
      accA[2] += ex * lo2f(wA.y); accA[3] += ex * hi2f(wA.y);
    }
    if (pB < eB) {
      float e = asB + advB;
      e = fmaxf(e, 0.2f * e);
      float ex = __expf(e);
      lB += ex;
      accB[0] += ex * lo2f(wB.x); accB[1] += ex * hi2f(wB.x);
      accB[2] += ex * lo2f(wB.y); accB[3] += ex * hi2f(wB.y);
    }
    wA = wnA; wB = wnB; asA = anA; asB = anB;
    sA1 = sA2; sB1 = sB2;
    pA = p1A; pB = p1B; p1A = p2A; p1B = p2B;
  }
#pragma unroll
  for (int off = 8; off <= 32; off <<= 1) {
#pragma unroll
    for (int i = 0; i < 4; i++) {
      accA[i] += __shfl_xor(accA[i], off, 64);
      accB[i] += __shfl_xor(accB[i], off, 64);
    }
    lA += __shfl_xor(lA, off, 64);
    lB += __shfl_xor(lB, off, 64);
  }
  if (slot < 2) {
    int node = slot == 0 ? nA : nB;
    float lsum = slot == 0 ? lA : lB;
    float li = 1.f / (lsum + 1e-16f);
    int fb = fl * 4;
    float o[4];
#pragma unroll
    for (int i = 0; i < 4; i++) {
      int j = fb + i;
      float av = slot == 0 ? accA[i] : accB[i];
      float ov = av * li + b2v[j];
      ov = (ov - m[j]) * rsqrtf(v[j] + 1e-5f) * g[j] + bb[j];
      o[i] = fmaxf(ov, 0.f);
    }
    *(float4*)(out_emb + node * OUTD + fb) = make_float4(o[0], o[1], o[2], o[3]);
  }
}

// ---------- classifier + regressor heads (thread per node) ----------
__global__ __launch_bounds__(256) void k_mlp(
    const float* __restrict__ embf,
    const float* __restrict__ cw1, const float* __restrict__ cb1,
    const float* __restrict__ cw2, const float* __restrict__ cb2,
    const float* __restrict__ rw1, const float* __restrict__ rb1,
    const float* __restrict__ rw2, const float* __restrict__ rb2,
    float* __restrict__ out_roles, float* __restrict__ out_energy) {
  __shared__ float C1[OUTD * HID2D], R1[OUTD * HID2D];
  __shared__ float C2[HID2D * 3], CB1[HID2D], RB1[HID2D], R2[HID2D];
  __shared__ float CB2v[3], RB2v;
  int t = threadIdx.x;
  for (int i = t; i < OUTD * HID2D; i += 256) { C1[i] = cw1[i]; R1[i] = rw1[i]; }
  if (t < HID2D) { CB1[t] = cb1[t]; RB1[t] = rb1[t]; R2[t] = rw2[t]; }
  if (t < HID2D * 3) C2[t] = cw2[t];
  if (t < 3) CB2v[t] = cb2[t];
  if (t == 0) RB2v = rb2[0];
  __syncthreads();
  int node = blockIdx.x * 256 + t;
  if (node >= NN) return;
  float e[OUTD];
#pragma unroll
  for (int k = 0; k < OUTD; k++) e[k] = embf[node * OUTD + k];
  float r0 = CB2v[0], r1 = CB2v[1], r2 = CB2v[2], en = RB2v;
  for (int j = 0; j < HID2D; j++) {
    float hc = CB1[j], hr = RB1[j];
#pragma unroll
    for (int k = 0; k < OUTD; k++) {
      hc += e[k] * C1[k * HID2D + j];
      hr += e[k] * R1[k * HID2D + j];
    }
    hc = fmaxf(hc, 0.f);
    hr = fmaxf(hr, 0.f);
    r0 += hc * C2[j * 3 + 0];
    r1 += hc * C2[j * 3 + 1];
    r2 += hc * C2[j * 3 + 2];
    en += hr * R2[j];
  }
  out_roles[node * 3 + 0] = r0;
  out_roles[node * 3 + 1] = r1;
  out_roles[node * 3 + 2] = r2;
  out_energy[node] = en;
}

extern "C" void kernel_launch(void* const* d_in, const int* in_sizes, int n_in,
                              void* d_out, int out_size, void* d_ws, size_t ws_size,
                              hipStream_t stream) {
  const float* x    = (const float*)d_in[0];
  const int*   ei   = (const int*)d_in[1];
  const float* W1   = (const float*)d_in[2];
  const float* as1w = (const float*)d_in[3];
  const float* ad1w = (const float*)d_in[4];
  const float* b1   = (const float*)d_in[5];
  const float* W2   = (const float*)d_in[6];
  const float* as2w = (const float*)d_in[7];
  const float* ad2w = (const float*)d_in[8];
  const float* b2v  = (const float*)d_in[9];
  const float* bn1g = (const float*)d_in[10];
  const float* bn1b = (const float*)d_in[11];
  const float* bn1m = (const float*)d_in[12];
  const float* bn1v = (const float*)d_in[13];
  const float* bn2g = (const float*)d_in[14];
  const float* bn2b = (const float*)d_in[15];
  const float* bn2m = (const float*)d_in[16];
  const float* bn2v = (const float*)d_in[17];
  const float* cw1  = (const float*)d_in[18];
  const float* cb1  = (const float*)d_in[19];
  const float* cw2  = (const float*)d_in[20];
  const float* cb2  = (const float*)d_in[21];
  const float* rw1  = (const float*)d_in[22];
  const float* rb1  = (const float*)d_in[23];
  const float* rw2  = (const float*)d_in[24];
  const float* rb2  = (const float*)d_in[25];

  // workspace (~56 MB), no aliasing
  uint*  h1u = (uint*)d_ws;               // N*32 uints (bf16x2) = 12.8MB
  float* hbn = (float*)(h1u + NN * 32);   // N*64 f32 = 25.6MB
  float* as1 = hbn + NN * HIDD;           // N*4
  float* ad1 = as1 + NN * NHEADS;         // N*4
  int* rowp  = (int*)(ad1 + NN * NHEADS); // N+1
  int* srcs  = rowp + NN + 1;             // ETOT + 64 pad
  int* bcur  = srcs + ETOT + 64;          // 512
  int* bins  = bcur + 512;                // NBUCK*CAP = 2.0M ints (8MB)
  uint* h2u  = h1u;                       // N*16 uints fits h1u slot (h1 dead)
  float* as2 = as1;
  float* ad2 = ad1;

  float* out        = (float*)d_out;
  float* out_emb    = out;                   // N*32
  float* out_roles  = out + NN * OUTD;       // N*3
  float* out_energy = out + NN * (OUTD + 3); // N*1

  hipMemsetAsync(bcur, 0, 512 * sizeof(int), stream);
  k_pre<<<NBBIN + NBLIN1, 256, 0, stream>>>(ei, bcur, bins, x, W1, as1w, ad1w, h1u, as1, ad1);
  k_csr<<<NBUCK, 256, 0, stream>>>(bcur, bins, rowp, srcs);
  k_agg1<<<NN / 8, 256, 0, stream>>>(rowp, srcs, h1u, as1, ad1, b1, bn1g, bn1b, bn1m, bn1v, hbn);
  k_lin2<<<NN / 16, 256, 0, stream>>>(hbn, W2, as2w, ad2w, h2u, as2, ad2);
  k_agg2<<<NN / 8, 256, 0, stream>>>(rowp, srcs, h2u, as2, ad2, b2v, bn2g, bn2b, bn2m, bn2v, out_emb);
  k_mlp<<<(NN + 255) / 256, 256, 0, stream>>>(out_emb, cw1, cb1, cw2, cb2, rw1, rb1, rw2, rb2, out_roles, out_energy);
}

// Round 13
// 327.292 us; speedup vs baseline: 1.0098x; 1.0098x over previous
//
#include <hip/hip_runtime.h>
#include <hip/hip_bf16.h>

#define NN 100000
#define EE 1600000
#define ETOT (EE + NN)          // 1,700,000 edges incl. self-loops
#define IND 32
#define HIDD 64
#define NHEADS 4
#define OUTD 32
#define HID2D 32

#define BSH 8                   // 256 nodes per bucket
#define NBUCK 391               // ceil(NN / 256)
#define CAP 5120                // max edges per bucket (mean ~4348)
#define EPB 8192                // edges per bin block (count + rescatter)

typedef unsigned int uint;

__device__ __forceinline__ uint pack2(float a, float b) {
  uint lo = (uint)__bfloat16_as_ushort(__float2bfloat16(a));
  uint hi = (uint)__bfloat16_as_ushort(__float2bfloat16(b));
  return (hi << 16) | lo;
}
__device__ __forceinline__ float lo2f(uint w) { return __uint_as_float(w << 16); }
__device__ __forceinline__ float hi2f(uint w) { return __uint_as_float(w & 0xFFFF0000u); }

// ---------- linear 1: h1(bf16) = x @ W1 ; as1/ad1 f32 attention dots ----------
__global__ __launch_bounds__(256) void k_lin1(
    const float* __restrict__ x, const float* __restrict__ W1,
    const float* __restrict__ atsrc, const float* __restrict__ atdst,
    uint* __restrict__ h1u, float* __restrict__ as1, float* __restrict__ ad1) {
  __shared__ float Ws[IND * HIDD];
  __shared__ float xs[8 * IND];
  __shared__ float atS[HIDD], atD[HIDD];
  int t = threadIdx.x;
  for (int i = t; i < IND * HIDD; i += 256) Ws[i] = W1[i];
  if (t < HIDD) { atS[t] = atsrc[t]; atD[t] = atdst[t]; }
  xs[t] = x[blockIdx.x * 256 + t];
  __syncthreads();
  int nl = t >> 5, tl = t & 31;
  int node = blockIdx.x * 8 + nl;
  int j0 = 2 * tl, j1 = j0 + 1;
  float a0 = 0.f, a1 = 0.f;
#pragma unroll
  for (int k = 0; k < IND; k++) {
    float xv = xs[nl * IND + k];
    a0 += xv * Ws[k * HIDD + j0];
    a1 += xv * Ws[k * HIDD + j1];
  }
  h1u[node * 32 + tl] = pack2(a0, a1);
  float ps = a0 * atS[j0] + a1 * atS[j1];
  float pd = a0 * atD[j0] + a1 * atD[j1];
#pragma unroll
  for (int off = 4; off >= 1; off >>= 1) {
    ps += __shfl_down(ps, off, 8);
    pd += __shfl_down(pd, off, 8);
  }
  if ((tl & 7) == 0) {
    as1[node * NHEADS + (tl >> 3)] = ps;
    ad1[node * NHEADS + (tl >> 3)] = pd;
  }
}

// ---------- linear 2: h2(bf16) = hbn(f32) @ W2 ; as2/ad2 ----------
__global__ __launch_bounds__(256) void k_lin2(
    const float* __restrict__ hbn, const float* __restrict__ W2,
    const float* __restrict__ atsrc, const float* __restrict__ atdst,
    uint* __restrict__ h2u, float* __restrict__ as2, float* __restrict__ ad2) {
  __shared__ float Ws[HIDD * OUTD];
  __shared__ float xs[16 * HIDD];
  __shared__ float atS[OUTD], atD[OUTD];
  int t = threadIdx.x;
  for (int i = t; i < HIDD * OUTD; i += 256) Ws[i] = W2[i];
  if (t < OUTD) { atS[t] = atsrc[t]; atD[t] = atdst[t]; }
  for (int i = t; i < 16 * HIDD; i += 256) xs[i] = hbn[blockIdx.x * 16 * HIDD + i];
  __syncthreads();
  int nl = t >> 4, tl = t & 15;
  int node = blockIdx.x * 16 + nl;
  int j0 = 2 * tl, j1 = j0 + 1;
  float a0 = 0.f, a1 = 0.f;
#pragma unroll
  for (int k = 0; k < HIDD; k++) {
    float xv = xs[nl * HIDD + k];
    a0 += xv * Ws[k * OUTD + j0];
    a1 += xv * Ws[k * OUTD + j1];
  }
  h2u[node * 16 + tl] = pack2(a0, a1);
  float ps = a0 * atS[j0] + a1 * atS[j1];
  float pd = a0 * atD[j0] + a1 * atD[j1];
#pragma unroll
  for (int off = 8; off >= 1; off >>= 1) {
    ps += __shfl_down(ps, off, 16);
    pd += __shfl_down(pd, off, 16);
  }
  if (tl == 0) { as2[node] = ps; ad2[node] = pd; }
}

// ---------- pass 1: bucket edges by dst>>8 (count, reserve, re-read & scatter) ----------
__global__ __launch_bounds__(256) void k_bin(const int* __restrict__ ei,
                                             int* __restrict__ bcur,
                                             int* __restrict__ bins) {
  __shared__ int cnt[NBUCK];
  int t = threadIdx.x;
  for (int i = t; i < NBUCK; i += 256) cnt[i] = 0;
  __syncthreads();
  int base = blockIdx.x * EPB;
  int lim = base + EPB; if (lim > ETOT) lim = ETOT;
  for (int i = base + t; i < lim; i += 256) {
    int d = (i < EE) ? ei[EE + i] : (i - EE);
    atomicAdd(&cnt[d >> BSH], 1);
  }
  __syncthreads();
  // reserve this block's range in each bucket; cnt becomes the running cursor
  for (int i = t; i < NBUCK; i += 256) cnt[i] = atomicAdd(&bcur[i], cnt[i]);
  __syncthreads();
  for (int i = base + t; i < lim; i += 256) {
    int s, d;
    if (i < EE) { s = ei[i]; d = ei[EE + i]; } else { s = i - EE; d = s; }
    int bk = d >> BSH;
    int pos = atomicAdd(&cnt[bk], 1);
    bins[bk * CAP + pos] = (s << BSH) | (d & ((1 << BSH) - 1));
  }
}

// ---------- pass 2: per-bucket local CSR (391 blocks), inline 512-scan ----------
// srcs entries are stored PRE-SCALED by 8 (uint4/uint2 row offsets).
__global__ __launch_bounds__(256) void k_csr(const int* __restrict__ bcur,
                                             const int* __restrict__ bins,
                                             int* __restrict__ rowp,
                                             int* __restrict__ srcs) {
  __shared__ int lrec[CAP];          // 20KB
  __shared__ int sA[512], sB[512];
  __shared__ int ldeg[256];
  int b = blockIdx.x, t = threadIdx.x;
  if (b == 0) {                      // zero the 64-entry pad past ETOT
    if (t < 64) srcs[ETOT + t] = 0;
    if (t == 0) rowp[NN] = ETOT;
  }
  // inline exclusive scan of the NBUCK bucket counts
  sA[t] = (t < NBUCK) ? bcur[t] : 0;
  sA[t + 256] = (t + 256 < NBUCK) ? bcur[t + 256] : 0;
  __syncthreads();
  int* in = sA; int* out = sB;
  for (int off = 1; off < 512; off <<= 1) {
    for (int i = t; i < 512; i += 256)
      out[i] = in[i] + ((i >= off) ? in[i - off] : 0);
    __syncthreads();
    int* tmp = in; in = out; out = tmp;
  }
  int gb = (b == 0) ? 0 : in[b - 1];
  __syncthreads();
  int count = bcur[b]; if (count > CAP) count = CAP;
  ldeg[t] = 0;
  __syncthreads();
  for (int i = t; i < count; i += 256) {
    int r = bins[b * CAP + i];
    lrec[i] = r;
    atomicAdd(&ldeg[r & 255], 1);
  }
  __syncthreads();
  int dv = ldeg[t];
  sA[t] = dv;
  __syncthreads();
  in = sA; out = sB;
  for (int off = 1; off < 256; off <<= 1) {
    out[t] = in[t] + ((t >= off) ? in[t - off] : 0);
    __syncthreads();
    int* tmp = in; in = out; out = tmp;
  }
  int nb = b << BSH;
  int ex = in[t] - dv;               // exclusive scan
  if (nb + t < NN) rowp[nb + t] = gb + ex;
  ldeg[t] = ex;                      // reuse as scatter cursor
  __syncthreads();
  for (int i = t; i < count; i += 256) {
    int r = lrec[i];
    int pos = atomicAdd(&ldeg[r & 255], 1);
    srcs[gb + pos] = (r >> BSH) << 3;   // pre-scaled src*8
  }
}

// ---------- GAT1 aggregation + bias + BN1 + ReLU, DUAL-node waves ----------
// srcs pre-scaled by 8; pad past ETOT allows unclamped prefetch.
__global__ __launch_bounds__(256, 4) void k_agg1(
    const int* __restrict__ rowp, const int* __restrict__ srcs,
    const uint* __restrict__ h1u, const float* __restrict__ as1,
    const float* __restrict__ ad1, const float* __restrict__ b1,
    const float* __restrict__ g, const float* __restrict__ bb,
    const float* __restrict__ m, const float* __restrict__ v,
    float* __restrict__ hbn) {
  int t = threadIdx.x;
  int wid = t >> 6, lane = t & 63;
  int nA = blockIdx.x * 8 + wid * 2;
  int nB = nA + 1;
  int slot = lane >> 3;
  int fl = lane & 7;
  int hd = fl >> 1;
  int stA = rowp[nA], eA = rowp[nA + 1], eB = rowp[nB + 1];
  int stB = eA;
  float advA = ad1[nA * NHEADS + hd];
  float advB = ad1[nB * NHEADS + hd];
  const uint4* h14 = (const uint4*)h1u;
  float accA[8] = {0,0,0,0,0,0,0,0}, accB[8] = {0,0,0,0,0,0,0,0};
  float lA = 0.f, lB = 0.f;
  int pA = stA + slot, pB = stB + slot;
  int sA0 = srcs[pA];                 // pre-scaled s*8, pad-safe
  int sB0 = srcs[pB];
  uint4 wA = h14[sA0 + fl];
  uint4 wB = h14[sB0 + fl];
  float asA = as1[(sA0 >> 1) + hd];
  float asB = as1[(sB0 >> 1) + hd];
  int p1A = pA + 8, p1B = pB + 8;
  int sA1 = srcs[p1A];
  int sB1 = srcs[p1B];
  while (pA < eA || pB < eB) {
    uint4 wnA = h14[sA1 + fl];
    uint4 wnB = h14[sB1 + fl];
    float anA = as1[(sA1 >> 1) + hd];
    float anB = as1[(sB1 >> 1) + hd];
    int p2A = p1A + 8, p2B = p1B + 8;
    int sA2 = srcs[p2A < ETOT ? p2A : ETOT];
    int sB2 = srcs[p2B < ETOT ? p2B : ETOT];
    if (pA < eA) {
      float e = asA + advA;
      e = fmaxf(e, 0.2f * e);
      float ex = __expf(e);
      lA += ex;
      accA[0] += ex * lo2f(wA.x); accA[1] += ex * hi2f(wA.x);
      accA[2] += ex * lo2f(wA.y); accA[3] += ex * hi2f(wA.y);
      accA[4] += ex * lo2f(wA.z); accA[5] += ex * hi2f(wA.z);
      accA[6] += ex * lo2f(wA.w); accA[7] += ex * hi2f(wA.w);
    }
    if (pB < eB) {
      float e = asB + advB;
      e = fmaxf(e, 0.2f * e);
      float ex = __expf(e);
      lB += ex;
      accB[0] += ex * lo2f(wB.x); accB[1] += ex * hi2f(wB.x);
      accB[2] += ex * lo2f(wB.y); accB[3] += ex * hi2f(wB.y);
      accB[4] += ex * lo2f(wB.z); accB[5] += ex * hi2f(wB.z);
      accB[6] += ex * lo2f(wB.w); accB[7] += ex * hi2f(wB.w);
    }
    wA = wnA; wB = wnB; asA = anA; asB = anB;
    sA1 = sA2; sB1 = sB2;
    pA = p1A; pB = p1B; p1A = p2A; p1B = p2B;
  }
#pragma unroll
  for (int off = 8; off <= 32; off <<= 1) {
#pragma unroll
    for (int i = 0; i < 8; i++) {
      accA[i] += __shfl_xor(accA[i], off, 64);
      accB[i] += __shfl_xor(accB[i], off, 64);
    }
    lA += __shfl_xor(lA, off, 64);
    lB += __shfl_xor(lB, off, 64);
  }
  if (slot < 2) {
    int node = slot == 0 ? nA : nB;
    float lsum = slot == 0 ? lA : lB;
    float li = 1.f / (lsum + 1e-16f);
    int fb = fl * 8;
    float o[8];
#pragma unroll
    for (int i = 0; i < 8; i++) {
      int j = fb + i;
      float av = slot == 0 ? accA[i] : accB[i];
      float ov = av * li + b1[j];
      ov = (ov - m[j]) * rsqrtf(v[j] + 1e-5f) * g[j] + bb[j];
      o[i] = fmaxf(ov, 0.f);
    }
    float4* dst = (float4*)(hbn + node * HIDD + fb);
    dst[0] = make_float4(o[0], o[1], o[2], o[3]);
    dst[1] = make_float4(o[4], o[5], o[6], o[7]);
  }
}

// ---------- GAT2 aggregation + bias + BN2 + ReLU, DUAL-node waves ----------
__global__ __launch_bounds__(256, 4) void k_agg2(
    const int* __restrict__ rowp, const int* __restrict__ srcs,
    const uint* __restrict__ h2u, const float* __restrict__ as2,
    const float* __restrict__ ad2, const float* __restrict__ b2v,
    const float* __restrict__ g, const float* __restrict__ bb,
    const float* __restrict__ m, const float* __restrict__ v,
    float* __restrict__ out_emb) {
  int t = threadIdx.x;
  int wid = t >> 6, lane = t & 63;
  int nA = blockIdx.x * 8 + wid * 2;
  int nB = nA + 1;
  int slot = lane >> 3;
  int fl = lane & 7;         // feats fl*4..fl*4+3
  int stA = rowp[nA], eA = rowp[nA + 1], eB = rowp[nB + 1];
  int stB = eA;
  float advA = ad2[nA], advB = ad2[nB];
  const uint2* h22 = (const uint2*)h2u;
  float accA[4] = {0,0,0,0}, accB[4] = {0,0,0,0};
  float lA = 0.f, lB = 0.f;
  int pA = stA + slot, pB = stB + slot;
  int sA0 = srcs[pA];                 // pre-scaled s*8 (= uint2 row offset)
  int sB0 = srcs[pB];
  uint2 wA = h22[sA0 + fl];
  uint2 wB = h22[sB0 + fl];
  float asA = as2[sA0 >> 3], asB = as2[sB0 >> 3];
  int p1A = pA + 8, p1B = pB + 8;
  int sA1 = srcs[p1A];
  int sB1 = srcs[p1B];
  while (pA < eA || pB < eB) {
    uint2 wnA = h22[sA1 + fl];
    uint2 wnB = h22[sB1 + fl];
    float anA = as2[sA1 >> 3], anB = as2[sB1 >> 3];
    int p2A = p1A + 8, p2B = p1B + 8;
    int sA2 = srcs[p2A < ETOT ? p2A : ETOT];
    int sB2 = srcs[p2B < ETOT ? p2B : ETOT];
    if (pA < eA) {
      float e = asA + advA;
      e = fmaxf(e, 0.2f * e);
      float ex = __expf(e);
      lA += ex;
      accA[0] += ex * lo2f(wA.x); accA[1] += ex * hi2f(wA.x);
      accA[2] += ex * lo2f(wA.y); accA[3] += ex * hi2f(wA.y);
    }
    if (pB < eB) {
      float e = asB + advB;
      e = fmaxf(e, 0.2f * e);
      float ex = __expf(e);
      lB += ex;
      accB[0] += ex * lo2f(wB.x); accB[1] += ex * hi2f(wB.x);
      accB[2] += ex * lo2f(wB.y); accB[3] += ex * hi2f(wB.y);
    }
    wA = wnA; wB = wnB; asA = anA; asB = anB;
    sA1 = sA2; sB1 = sB2;
    pA = p1A; pB = p1B; p1A = p2A; p1B = p2B;
  }
#pragma unroll
  for (int off = 8; off <= 32; off <<= 1) {
#pragma unroll
    for (int i = 0; i < 4; i++) {
      accA[i] += __shfl_xor(accA[i], off, 64);
      accB[i] += __shfl_xor(accB[i], off, 64);
    }
    lA += __shfl_xor(lA, off, 64);
    lB += __shfl_xor(lB, off, 64);
  }
  if (slot < 2) {
    int node = slot == 0 ? nA : nB;
    float lsum = slot == 0 ? lA : lB;
    float li = 1.f / (lsum + 1e-16f);
    int fb = fl * 4;
    float o[4];
#pragma unroll
    for (int i = 0; i < 4; i++) {
      int j = fb + i;
      float av = slot == 0 ? accA[i] : accB[i];
      float ov = av * li + b2v[j];
      ov = (ov - m[j]) * rsqrtf(v[j] + 1e-5f) * g[j] + bb[j];
      o[i] = fmaxf(ov, 0.f);
    }
    *(float4*)(out_emb + node * OUTD + fb) = make_float4(o[0], o[1], o[2], o[3]);
  }
}

// ---------- classifier + regressor heads (thread per node) ----------
__global__ __launch_bounds__(256) void k_mlp(
    const float* __restrict__ embf,
    const float* __restrict__ cw1, const float* __restrict__ cb1,
    const float* __restrict__ cw2, const float* __restrict__ cb2,
    const float* __restrict__ rw1, const float* __restrict__ rb1,
    const float* __restrict__ rw2, const float* __restrict__ rb2,
    float* __restrict__ out_roles, float* __restrict__ out_energy) {
  __shared__ float C1[OUTD * HID2D], R1[OUTD * HID2D];
  __shared__ float C2[HID2D * 3], CB1[HID2D], RB1[HID2D], R2[HID2D];
  __shared__ float CB2v[3], RB2v;
  int t = threadIdx.x;
  for (int i = t; i < OUTD * HID2D; i += 256) { C1[i] = cw1[i]; R1[i] = rw1[i]; }
  if (t < HID2D) { CB1[t] = cb1[t]; RB1[t] = rb1[t]; R2[t] = rw2[t]; }
  if (t < HID2D * 3) C2[t] = cw2[t];
  if (t < 3) CB2v[t] = cb2[t];
  if (t == 0) RB2v = rb2[0];
  __syncthreads();
  int node = blockIdx.x * 256 + t;
  if (node >= NN) return;
  float e[OUTD];
#pragma unroll
  for (int k = 0; k < OUTD; k++) e[k] = embf[node * OUTD + k];
  float r0 = CB2v[0], r1 = CB2v[1], r2 = CB2v[2], en = RB2v;
  for (int j = 0; j < HID2D; j++) {
    float hc = CB1[j], hr = RB1[j];
#pragma unroll
    for (int k = 0; k < OUTD; k++) {
      hc += e[k] * C1[k * HID2D + j];
      hr += e[k] * R1[k * HID2D + j];
    }
    hc = fmaxf(hc, 0.f);
    hr = fmaxf(hr, 0.f);
    r0 += hc * C2[j * 3 + 0];
    r1 += hc * C2[j * 3 + 1];
    r2 += hc * C2[j * 3 + 2];
    en += hr * R2[j];
  }
  out_roles[node * 3 + 0] = r0;
  out_roles[node * 3 + 1] = r1;
  out_roles[node * 3 + 2] = r2;
  out_energy[node] = en;
}

extern "C" void kernel_launch(void* const* d_in, const int* in_sizes, int n_in,
                              void* d_out, int out_size, void* d_ws, size_t ws_size,
                              hipStream_t stream) {
  const float* x    = (const float*)d_in[0];
  const int*   ei   = (const int*)d_in[1];
  const float* W1   = (const float*)d_in[2];
  const float* as1w = (const float*)d_in[3];
  const float* ad1w = (const float*)d_in[4];
  const float* b1   = (const float*)d_in[5];
  const float* W2   = (const float*)d_in[6];
  const float* as2w = (const float*)d_in[7];
  const float* ad2w = (const float*)d_in[8];
  const float* b2v  = (const float*)d_in[9];
  const float* bn1g = (const float*)d_in[10];
  const float* bn1b = (const float*)d_in[11];
  const float* bn1m = (const float*)d_in[12];
  const float* bn1v = (const float*)d_in[13];
  const float* bn2g = (const float*)d_in[14];
  const float* bn2b = (const float*)d_in[15];
  const float* bn2m = (const float*)d_in[16];
  const float* bn2v = (const float*)d_in[17];
  const float* cw1  = (const float*)d_in[18];
  const float* cb1  = (const float*)d_in[19];
  const float* cw2  = (const float*)d_in[20];
  const float* cb2  = (const float*)d_in[21];
  const float* rw1  = (const float*)d_in[22];
  const float* rb1  = (const float*)d_in[23];
  const float* rw2  = (const float*)d_in[24];
  const float* rb2  = (const float*)d_in[25];

  // workspace (~56 MB), no aliasing
  uint*  h1u = (uint*)d_ws;               // N*32 uints (bf16x2) = 12.8MB
  float* hbn = (float*)(h1u + NN * 32);   // N*64 f32 = 25.6MB
  float* as1 = hbn + NN * HIDD;           // N*4
  float* ad1 = as1 + NN * NHEADS;         // N*4
  int* rowp  = (int*)(ad1 + NN * NHEADS); // N+1
  int* srcs  = rowp + NN + 1;             // ETOT + 64 pad
  int* bcur  = srcs + ETOT + 64;          // 512
  int* bins  = bcur + 512;                // NBUCK*CAP = 2.0M ints (8MB)
  uint* h2u  = h1u;                       // N*16 uints fits h1u slot (h1 dead)
  float* as2 = as1;
  float* ad2 = ad1;

  float* out        = (float*)d_out;
  float* out_emb    = out;                   // N*32
  float* out_roles  = out + NN * OUTD;       // N*3
  float* out_energy = out + NN * (OUTD + 3); // N*1

  hipMemsetAsync(bcur, 0, 512 * sizeof(int), stream);
  k_bin<<<(ETOT + EPB - 1) / EPB, 256, 0, stream>>>(ei, bcur, bins);
  k_csr<<<NBUCK, 256, 0, stream>>>(bcur, bins, rowp, srcs);
  k_lin1<<<NN / 8, 256, 0, stream>>>(x, W1, as1w, ad1w, h1u, as1, ad1);
  k_agg1<<<NN / 8, 256, 0, stream>>>(rowp, srcs, h1u, as1, ad1, b1, bn1g, bn1b, bn1m, bn1v, hbn);
  k_lin2<<<NN / 16, 256, 0, stream>>>(hbn, W2, as2w, ad2w, h2u, as2, ad2);
  k_agg2<<<NN / 8, 256, 0, stream>>>(rowp, srcs, h2u, as2, ad2, b2v, bn2g, bn2b, bn2m, bn2v, out_emb);
  k_mlp<<<(NN + 255) / 256, 256, 0, stream>>>(out_emb, cw1, cb1, cw2, cb2, rw1, rb1, rw2, rb2, out_roles, out_energy);
}

// Round 14
// 320.921 us; speedup vs baseline: 1.0299x; 1.0199x over previous
//
#include <hip/hip_runtime.h>
#include <hip/hip_bf16.h>

#define NN 100000
#define EE 1600000
#define ETOT (EE + NN)          // 1,700,000 edges incl. self-loops
#define IND 32
#define HIDD 64
#define NHEADS 4
#define OUTD 32
#define HID2D 32

#define BSH 8                   // 256 nodes per bucket
#define NBUCK 391               // ceil(NN / 256)
#define CAP 5120                // max edges per bucket (mean ~4348)
#define EPB 8192                // edges per bin block (count + rescatter)

typedef unsigned int uint;

__device__ __forceinline__ uint pack2(float a, float b) {
  uint lo = (uint)__bfloat16_as_ushort(__float2bfloat16(a));
  uint hi = (uint)__bfloat16_as_ushort(__float2bfloat16(b));
  return (hi << 16) | lo;
}
__device__ __forceinline__ float lo2f(uint w) { return __uint_as_float(w << 16); }
__device__ __forceinline__ float hi2f(uint w) { return __uint_as_float(w & 0xFFFF0000u); }

// ---------- linear 1: h1(bf16) = x @ W1 ; as1/ad1 f32 attention dots ----------
__global__ __launch_bounds__(256) void k_lin1(
    const float* __restrict__ x, const float* __restrict__ W1,
    const float* __restrict__ atsrc, const float* __restrict__ atdst,
    uint* __restrict__ h1u, float* __restrict__ as1, float* __restrict__ ad1) {
  __shared__ float Ws[IND * HIDD];
  __shared__ float xs[8 * IND];
  __shared__ float atS[HIDD], atD[HIDD];
  int t = threadIdx.x;
  for (int i = t; i < IND * HIDD; i += 256) Ws[i] = W1[i];
  if (t < HIDD) { atS[t] = atsrc[t]; atD[t] = atdst[t]; }
  xs[t] = x[blockIdx.x * 256 + t];
  __syncthreads();
  int nl = t >> 5, tl = t & 31;
  int node = blockIdx.x * 8 + nl;
  int j0 = 2 * tl, j1 = j0 + 1;
  float a0 = 0.f, a1 = 0.f;
#pragma unroll
  for (int k = 0; k < IND; k++) {
    float xv = xs[nl * IND + k];
    a0 += xv * Ws[k * HIDD + j0];
    a1 += xv * Ws[k * HIDD + j1];
  }
  h1u[node * 32 + tl] = pack2(a0, a1);
  float ps = a0 * atS[j0] + a1 * atS[j1];
  float pd = a0 * atD[j0] + a1 * atD[j1];
#pragma unroll
  for (int off = 4; off >= 1; off >>= 1) {
    ps += __shfl_down(ps, off, 8);
    pd += __shfl_down(pd, off, 8);
  }
  if ((tl & 7) == 0) {
    as1[node * NHEADS + (tl >> 3)] = ps;
    ad1[node * NHEADS + (tl >> 3)] = pd;
  }
}

// ---------- linear 2: h2(bf16) = hbn(f32) @ W2 ; as2/ad2 ----------
__global__ __launch_bounds__(256) void k_lin2(
    const float* __restrict__ hbn, const float* __restrict__ W2,
    const float* __restrict__ atsrc, const float* __restrict__ atdst,
    uint* __restrict__ h2u, float* __restrict__ as2, float* __restrict__ ad2) {
  __shared__ float Ws[HIDD * OUTD];
  __shared__ float xs[16 * HIDD];
  __shared__ float atS[OUTD], atD[OUTD];
  int t = threadIdx.x;
  for (int i = t; i < HIDD * OUTD; i += 256) Ws[i] = W2[i];
  if (t < OUTD) { atS[t] = atsrc[t]; atD[t] = atdst[t]; }
  for (int i = t; i < 16 * HIDD; i += 256) xs[i] = hbn[blockIdx.x * 16 * HIDD + i];
  __syncthreads();
  int nl = t >> 4, tl = t & 15;
  int node = blockIdx.x * 16 + nl;
  int j0 = 2 * tl, j1 = j0 + 1;
  float a0 = 0.f, a1 = 0.f;
#pragma unroll
  for (int k = 0; k < HIDD; k++) {
    float xv = xs[nl * HIDD + k];
    a0 += xv * Ws[k * OUTD + j0];
    a1 += xv * Ws[k * OUTD + j1];
  }
  h2u[node * 16 + tl] = pack2(a0, a1);
  float ps = a0 * atS[j0] + a1 * atS[j1];
  float pd = a0 * atD[j0] + a1 * atD[j1];
#pragma unroll
  for (int off = 8; off >= 1; off >>= 1) {
    ps += __shfl_down(ps, off, 16);
    pd += __shfl_down(pd, off, 16);
  }
  if (tl == 0) { as2[node] = ps; ad2[node] = pd; }
}

// ---------- pass 1: bucket edges by dst>>8 (count, reserve, re-read & scatter) ----------
__global__ __launch_bounds__(256) void k_bin(const int* __restrict__ ei,
                                             int* __restrict__ bcur,
                                             int* __restrict__ bins) {
  __shared__ int cnt[NBUCK];
  int t = threadIdx.x;
  for (int i = t; i < NBUCK; i += 256) cnt[i] = 0;
  __syncthreads();
  int base = blockIdx.x * EPB;
  int lim = base + EPB; if (lim > ETOT) lim = ETOT;
  for (int i = base + t; i < lim; i += 256) {
    int d = (i < EE) ? ei[EE + i] : (i - EE);
    atomicAdd(&cnt[d >> BSH], 1);
  }
  __syncthreads();
  for (int i = t; i < NBUCK; i += 256) cnt[i] = atomicAdd(&bcur[i], cnt[i]);
  __syncthreads();
  for (int i = base + t; i < lim; i += 256) {
    int s, d;
    if (i < EE) { s = ei[i]; d = ei[EE + i]; } else { s = i - EE; d = s; }
    int bk = d >> BSH;
    int pos = atomicAdd(&cnt[bk], 1);
    bins[bk * CAP + pos] = (s << BSH) | (d & ((1 << BSH) - 1));
  }
}

// ---------- pass 2: per-bucket local CSR (391 blocks), inline 512-scan ----------
// srcs entries are stored PRE-SCALED by 8 (uint4/uint2 row offsets).
__global__ __launch_bounds__(256) void k_csr(const int* __restrict__ bcur,
                                             const int* __restrict__ bins,
                                             int* __restrict__ rowp,
                                             int* __restrict__ srcs) {
  __shared__ int lrec[CAP];          // 20KB
  __shared__ int sA[512], sB[512];
  __shared__ int ldeg[256];
  int b = blockIdx.x, t = threadIdx.x;
  if (b == 0 && t == 0) rowp[NN] = ETOT;
  // inline exclusive scan of the NBUCK bucket counts
  sA[t] = (t < NBUCK) ? bcur[t] : 0;
  sA[t + 256] = (t + 256 < NBUCK) ? bcur[t + 256] : 0;
  __syncthreads();
  int* in = sA; int* out = sB;
  for (int off = 1; off < 512; off <<= 1) {
    for (int i = t; i < 512; i += 256)
      out[i] = in[i] + ((i >= off) ? in[i - off] : 0);
    __syncthreads();
    int* tmp = in; in = out; out = tmp;
  }
  int gb = (b == 0) ? 0 : in[b - 1];
  __syncthreads();
  int count = bcur[b]; if (count > CAP) count = CAP;
  ldeg[t] = 0;
  __syncthreads();
  for (int i = t; i < count; i += 256) {
    int r = bins[b * CAP + i];
    lrec[i] = r;
    atomicAdd(&ldeg[r & 255], 1);
  }
  __syncthreads();
  int dv = ldeg[t];
  sA[t] = dv;
  __syncthreads();
  in = sA; out = sB;
  for (int off = 1; off < 256; off <<= 1) {
    out[t] = in[t] + ((t >= off) ? in[t - off] : 0);
    __syncthreads();
    int* tmp = in; in = out; out = tmp;
  }
  int nb = b << BSH;
  int ex = in[t] - dv;               // exclusive scan
  if (nb + t < NN) rowp[nb + t] = gb + ex;
  ldeg[t] = ex;                      // reuse as scatter cursor
  __syncthreads();
  for (int i = t; i < count; i += 256) {
    int r = lrec[i];
    int pos = atomicAdd(&ldeg[r & 255], 1);
    srcs[gb + pos] = (r >> BSH) << 3;   // pre-scaled src*8
  }
}

// ---------- GAT1 aggregation + bias + BN1 + ReLU, DUAL-node waves ----------
// srcs pre-scaled by 8; prefetch clamped to lastp (stays on a hot row).
__global__ __launch_bounds__(256, 4) void k_agg1(
    const int* __restrict__ rowp, const int* __restrict__ srcs,
    const uint* __restrict__ h1u, const float* __restrict__ as1,
    const float* __restrict__ ad1, const float* __restrict__ b1,
    const float* __restrict__ g, const float* __restrict__ bb,
    const float* __restrict__ m, const float* __restrict__ v,
    float* __restrict__ hbn) {
  int t = threadIdx.x;
  int wid = t >> 6, lane = t & 63;
  int nA = blockIdx.x * 8 + wid * 2;
  int nB = nA + 1;
  int slot = lane >> 3;
  int fl = lane & 7;
  int hd = fl >> 1;
  int stA = rowp[nA], eA = rowp[nA + 1], eB = rowp[nB + 1];
  int stB = eA;
  int lpA = eA - 1, lpB = eB - 1;     // deg >= 1 (self-loop)
  float advA = ad1[nA * NHEADS + hd];
  float advB = ad1[nB * NHEADS + hd];
  const uint4* h14 = (const uint4*)h1u;
  float accA[8] = {0,0,0,0,0,0,0,0}, accB[8] = {0,0,0,0,0,0,0,0};
  float lA = 0.f, lB = 0.f;
  int pA = stA + slot, pB = stB + slot;
  int sA0 = srcs[pA < lpA ? pA : lpA];   // pre-scaled s*8
  int sB0 = srcs[pB < lpB ? pB : lpB];
  uint4 wA = h14[sA0 + fl];
  uint4 wB = h14[sB0 + fl];
  float asA = as1[(sA0 >> 1) + hd];
  float asB = as1[(sB0 >> 1) + hd];
  int p1A = pA + 8, p1B = pB + 8;
  int sA1 = srcs[p1A < lpA ? p1A : lpA];
  int sB1 = srcs[p1B < lpB ? p1B : lpB];
  while (pA < eA || pB < eB) {
    uint4 wnA = h14[sA1 + fl];
    uint4 wnB = h14[sB1 + fl];
    float anA = as1[(sA1 >> 1) + hd];
    float anB = as1[(sB1 >> 1) + hd];
    int p2A = p1A + 8, p2B = p1B + 8;
    int sA2 = srcs[p2A < lpA ? p2A : lpA];
    int sB2 = srcs[p2B < lpB ? p2B : lpB];
    if (pA < eA) {
      float e = asA + advA;
      e = fmaxf(e, 0.2f * e);
      float ex = __expf(e);
      lA += ex;
      accA[0] += ex * lo2f(wA.x); accA[1] += ex * hi2f(wA.x);
      accA[2] += ex * lo2f(wA.y); accA[3] += ex * hi2f(wA.y);
      accA[4] += ex * lo2f(wA.z); accA[5] += ex * hi2f(wA.z);
      accA[6] += ex * lo2f(wA.w); accA[7] += ex * hi2f(wA.w);
    }
    if (pB < eB) {
      float e = asB + advB;
      e = fmaxf(e, 0.2f * e);
      float ex = __expf(e);
      lB += ex;
      accB[0] += ex * lo2f(wB.x); accB[1] += ex * hi2f(wB.x);
      accB[2] += ex * lo2f(wB.y); accB[3] += ex * hi2f(wB.y);
      accB[4] += ex * lo2f(wB.z); accB[5] += ex * hi2f(wB.z);
      accB[6] += ex * lo2f(wB.w); accB[7] += ex * hi2f(wB.w);
    }
    wA = wnA; wB = wnB; asA = anA; asB = anB;
    sA1 = sA2; sB1 = sB2;
    pA = p1A; pB = p1B; p1A = p2A; p1B = p2B;
  }
#pragma unroll
  for (int off = 8; off <= 32; off <<= 1) {
#pragma unroll
    for (int i = 0; i < 8; i++) {
      accA[i] += __shfl_xor(accA[i], off, 64);
      accB[i] += __shfl_xor(accB[i], off, 64);
    }
    lA += __shfl_xor(lA, off, 64);
    lB += __shfl_xor(lB, off, 64);
  }
  if (slot < 2) {
    int node = slot == 0 ? nA : nB;
    float lsum = slot == 0 ? lA : lB;
    float li = 1.f / (lsum + 1e-16f);
    int fb = fl * 8;
    float o[8];
#pragma unroll
    for (int i = 0; i < 8; i++) {
      int j = fb + i;
      float av = slot == 0 ? accA[i] : accB[i];
      float ov = av * li + b1[j];
      ov = (ov - m[j]) * rsqrtf(v[j] + 1e-5f) * g[j] + bb[j];
      o[i] = fmaxf(ov, 0.f);
    }
    float4* dst = (float4*)(hbn + node * HIDD + fb);
    dst[0] = make_float4(o[0], o[1], o[2], o[3]);
    dst[1] = make_float4(o[4], o[5], o[6], o[7]);
  }
}

// ---------- GAT2 aggregation + bias + BN2 + ReLU, DUAL-node waves ----------
__global__ __launch_bounds__(256, 4) void k_agg2(
    const int* __restrict__ rowp, const int* __restrict__ srcs,
    const uint* __restrict__ h2u, const float* __restrict__ as2,
    const float* __restrict__ ad2, const float* __restrict__ b2v,
    const float* __restrict__ g, const float* __restrict__ bb,
    const float* __restrict__ m, const float* __restrict__ v,
    float* __restrict__ out_emb) {
  int t = threadIdx.x;
  int wid = t >> 6, lane = t & 63;
  int nA = blockIdx.x * 8 + wid * 2;
  int nB = nA + 1;
  int slot = lane >> 3;
  int fl = lane & 7;         // feats fl*4..fl*4+3
  int stA = rowp[nA], eA = rowp[nA + 1], eB = rowp[nB + 1];
  int stB = eA;
  int lpA = eA - 1, lpB = eB - 1;
  float advA = ad2[nA], advB = ad2[nB];
  const uint2* h22 = (const uint2*)h2u;
  float accA[4] = {0,0,0,0}, accB[4] = {0,0,0,0};
  float lA = 0.f, lB = 0.f;
  int pA = stA + slot, pB = stB + slot;
  int sA0 = srcs[pA < lpA ? pA : lpA];   // pre-scaled s*8 (= uint2 row offset)
  int sB0 = srcs[pB < lpB ? pB : lpB];
  uint2 wA = h22[sA0 + fl];
  uint2 wB = h22[sB0 + fl];
  float asA = as2[sA0 >> 3], asB = as2[sB0 >> 3];
  int p1A = pA + 8, p1B = pB + 8;
  int sA1 = srcs[p1A < lpA ? p1A : lpA];
  int sB1 = srcs[p1B < lpB ? p1B : lpB];
  while (pA < eA || pB < eB) {
    uint2 wnA = h22[sA1 + fl];
    uint2 wnB = h22[sB1 + fl];
    float anA = as2[sA1 >> 3], anB = as2[sB1 >> 3];
    int p2A = p1A + 8, p2B = p1B + 8;
    int sA2 = srcs[p2A < lpA ? p2A : lpA];
    int sB2 = srcs[p2B < lpB ? p2B : lpB];
    if (pA < eA) {
      float e = asA + advA;
      e = fmaxf(e, 0.2f * e);
      float ex = __expf(e);
      lA += ex;
      accA[0] += ex * lo2f(wA.x); accA[1] += ex * hi2f(wA.x);
      accA[2] += ex * lo2f(wA.y); accA[3] += ex * hi2f(wA.y);
    }
    if (pB < eB) {
      float e = asB + advB;
      e = fmaxf(e, 0.2f * e);
      float ex = __expf(e);
      lB += ex;
      accB[0] += ex * lo2f(wB.x); accB[1] += ex * hi2f(wB.x);
      accB[2] += ex * lo2f(wB.y); accB[3] += ex * hi2f(wB.y);
    }
    wA = wnA; wB = wnB; asA = anA; asB = anB;
    sA1 = sA2; sB1 = sB2;
    pA = p1A; pB = p1B; p1A = p2A; p1B = p2B;
  }
#pragma unroll
  for (int off = 8; off <= 32; off <<= 1) {
#pragma unroll
    for (int i = 0; i < 4; i++) {
      accA[i] += __shfl_xor(accA[i], off, 64);
      accB[i] += __shfl_xor(accB[i], off, 64);
    }
    lA += __shfl_xor(lA, off, 64);
    lB += __shfl_xor(lB, off, 64);
  }
  if (slot < 2) {
    int node = slot == 0 ? nA : nB;
    float lsum = slot == 0 ? lA : lB;
    float li = 1.f / (lsum + 1e-16f);
    int fb = fl * 4;
    float o[4];
#pragma unroll
    for (int i = 0; i < 4; i++) {
      int j = fb + i;
      float av = slot == 0 ? accA[i] : accB[i];
      float ov = av * li + b2v[j];
      ov = (ov - m[j]) * rsqrtf(v[j] + 1e-5f) * g[j] + bb[j];
      o[i] = fmaxf(ov, 0.f);
    }
    *(float4*)(out_emb + node * OUTD + fb) = make_float4(o[0], o[1], o[2], o[3]);
  }
}

// ---------- classifier + regressor heads (thread per node) ----------
__global__ __launch_bounds__(256) void k_mlp(
    const float* __restrict__ embf,
    const float* __restrict__ cw1, const float* __restrict__ cb1,
    const float* __restrict__ cw2, const float* __restrict__ cb2,
    const float* __restrict__ rw1, const float* __restrict__ rb1,
    const float* __restrict__ rw2, const float* __restrict__ rb2,
    float* __restrict__ out_roles, float* __restrict__ out_energy) {
  __shared__ float C1[OUTD * HID2D], R1[OUTD * HID2D];
  __shared__ float C2[HID2D * 3], CB1[HID2D], RB1[HID2D], R2[HID2D];
  __shared__ float CB2v[3], RB2v;
  int t = threadIdx.x;
  for (int i = t; i < OUTD * HID2D; i += 256) { C1[i] = cw1[i]; R1[i] = rw1[i]; }
  if (t < HID2D) { CB1[t] = cb1[t]; RB1[t] = rb1[t]; R2[t] = rw2[t]; }
  if (t < HID2D * 3) C2[t] = cw2[t];
  if (t < 3) CB2v[t] = cb2[t];
  if (t == 0) RB2v = rb2[0];
  __syncthreads();
  int node = blockIdx.x * 256 + t;
  if (node >= NN) return;
  float e[OUTD];
#pragma unroll
  for (int k = 0; k < OUTD; k++) e[k] = embf[node * OUTD + k];
  float r0 = CB2v[0], r1 = CB2v[1], r2 = CB2v[2], en = RB2v;
  for (int j = 0; j < HID2D; j++) {
    float hc = CB1[j], hr = RB1[j];
#pragma unroll
    for (int k = 0; k < OUTD; k++) {
      hc += e[k] * C1[k * HID2D + j];
      hr += e[k] * R1[k * HID2D + j];
    }
    hc = fmaxf(hc, 0.f);
    hr = fmaxf(hr, 0.f);
    r0 += hc * C2[j * 3 + 0];
    r1 += hc * C2[j * 3 + 1];
    r2 += hc * C2[j * 3 + 2];
    en += hr * R2[j];
  }
  out_roles[node * 3 + 0] = r0;
  out_roles[node * 3 + 1] = r1;
  out_roles[node * 3 + 2] = r2;
  out_energy[node] = en;
}

extern "C" void kernel_launch(void* const* d_in, const int* in_sizes, int n_in,
                              void* d_out, int out_size, void* d_ws, size_t ws_size,
                              hipStream_t stream) {
  const float* x    = (const float*)d_in[0];
  const int*   ei   = (const int*)d_in[1];
  const float* W1   = (const float*)d_in[2];
  const float* as1w = (const float*)d_in[3];
  const float* ad1w = (const float*)d_in[4];
  const float* b1   = (const float*)d_in[5];
  const float* W2   = (const float*)d_in[6];
  const float* as2w = (const float*)d_in[7];
  const float* ad2w = (const float*)d_in[8];
  const float* b2v  = (const float*)d_in[9];
  const float* bn1g = (const float*)d_in[10];
  const float* bn1b = (const float*)d_in[11];
  const float* bn1m = (const float*)d_in[12];
  const float* bn1v = (const float*)d_in[13];
  const float* bn2g = (const float*)d_in[14];
  const float* bn2b = (const float*)d_in[15];
  const float* bn2m = (const float*)d_in[16];
  const float* bn2v = (const float*)d_in[17];
  const float* cw1  = (const float*)d_in[18];
  const float* cb1  = (const float*)d_in[19];
  const float* cw2  = (const float*)d_in[20];
  const float* cb2  = (const float*)d_in[21];
  const float* rw1  = (const float*)d_in[22];
  const float* rb1  = (const float*)d_in[23];
  const float* rw2  = (const float*)d_in[24];
  const float* rb2  = (const float*)d_in[25];

  // workspace (~56 MB), no aliasing
  uint*  h1u = (uint*)d_ws;               // N*32 uints (bf16x2) = 12.8MB
  float* hbn = (float*)(h1u + NN * 32);   // N*64 f32 = 25.6MB
  float* as1 = hbn + NN * HIDD;           // N*4
  float* ad1 = as1 + NN * NHEADS;         // N*4
  int* rowp  = (int*)(ad1 + NN * NHEADS); // N+1
  int* srcs  = rowp + NN + 1;             // ETOT
  int* bcur  = srcs + ETOT;               // 512
  int* bins  = bcur + 512;                // NBUCK*CAP = 2.0M ints (8MB)
  uint* h2u  = h1u;                       // N*16 uints fits h1u slot (h1 dead)
  float* as2 = as1;
  float* ad2 = ad1;

  float* out        = (float*)d_out;
  float* out_emb    = out;                   // N*32
  float* out_roles  = out + NN * OUTD;       // N*3
  float* out_energy = out + NN * (OUTD + 3); // N*1

  hipMemsetAsync(bcur, 0, 512 * sizeof(int), stream);
  k_lin1<<<NN / 8, 256, 0, stream>>>(x, W1, as1w, ad1w, h1u, as1, ad1);
  k_bin<<<(ETOT + EPB - 1) / EPB, 256, 0, stream>>>(ei, bcur, bins);
  k_csr<<<NBUCK, 256, 0, stream>>>(bcur, bins, rowp, srcs);
  k_agg1<<<NN / 8, 256, 0, stream>>>(rowp, srcs, h1u, as1, ad1, b1, bn1g, bn1b, bn1m, bn1v, hbn);
  k_lin2<<<NN / 16, 256, 0, stream>>>(hbn, W2, as2w, ad2w, h2u, as2, ad2);
  k_agg2<<<NN / 8, 256, 0, stream>>>(rowp, srcs, h2u, as2, ad2, b2v, bn2g, bn2b, bn2m, bn2v, out_emb);
  k_mlp<<<(NN + 255) / 256, 256, 0, stream>>>(out_emb, cw1, cb1, cw2, cb2, rw1, rb1, rw2, rb2, out_roles, out_energy);
}

// Round 15
// 319.086 us; speedup vs baseline: 1.0358x; 1.0058x over previous
//
#include <hip/hip_runtime.h>
#include <hip/hip_bf16.h>

#define NN 100000
#define EE 1600000
#define ETOT (EE + NN)          // 1,700,000 edges incl. self-loops
#define IND 32
#define HIDD 64
#define NHEADS 4
#define OUTD 32
#define HID2D 32
#define LOG2E 1.44269504f

#define BSH 8                   // 256 nodes per bucket
#define NBUCK 391               // ceil(NN / 256)
#define CAP 5120                // max edges per bucket (mean ~4348)
#define EPB 8192                // edges per bin block (count + rescatter)

typedef unsigned int uint;

__device__ __forceinline__ uint pack2(float a, float b) {
  uint lo = (uint)__bfloat16_as_ushort(__float2bfloat16(a));
  uint hi = (uint)__bfloat16_as_ushort(__float2bfloat16(b));
  return (hi << 16) | lo;
}
__device__ __forceinline__ float lo2f(uint w) { return __uint_as_float(w << 16); }
// raw reinterpret: low 16 bits are the neighbor feature's bf16 acting as
// <=1-ulp mantissa noise — saves the AND per unpack (error ~ bf16 rounding).
__device__ __forceinline__ float hi2r(uint w) { return __uint_as_float(w); }

// ---------- linear 1: h1(bf16) = x @ W1 ; as1/ad1 (pre-scaled by log2e) ----------
__global__ __launch_bounds__(256) void k_lin1(
    const float* __restrict__ x, const float* __restrict__ W1,
    const float* __restrict__ atsrc, const float* __restrict__ atdst,
    uint* __restrict__ h1u, float* __restrict__ as1, float* __restrict__ ad1) {
  __shared__ float Ws[IND * HIDD];
  __shared__ float xs[8 * IND];
  __shared__ float atS[HIDD], atD[HIDD];
  int t = threadIdx.x;
  for (int i = t; i < IND * HIDD; i += 256) Ws[i] = W1[i];
  if (t < HIDD) { atS[t] = atsrc[t]; atD[t] = atdst[t]; }
  xs[t] = x[blockIdx.x * 256 + t];
  __syncthreads();
  int nl = t >> 5, tl = t & 31;
  int node = blockIdx.x * 8 + nl;
  int j0 = 2 * tl, j1 = j0 + 1;
  float a0 = 0.f, a1 = 0.f;
#pragma unroll
  for (int k = 0; k < IND; k++) {
    float xv = xs[nl * IND + k];
    a0 += xv * Ws[k * HIDD + j0];
    a1 += xv * Ws[k * HIDD + j1];
  }
  h1u[node * 32 + tl] = pack2(a0, a1);
  float ps = a0 * atS[j0] + a1 * atS[j1];
  float pd = a0 * atD[j0] + a1 * atD[j1];
#pragma unroll
  for (int off = 4; off >= 1; off >>= 1) {
    ps += __shfl_down(ps, off, 8);
    pd += __shfl_down(pd, off, 8);
  }
  if ((tl & 7) == 0) {
    as1[node * NHEADS + (tl >> 3)] = ps * LOG2E;
    ad1[node * NHEADS + (tl >> 3)] = pd * LOG2E;
  }
}

// ---------- linear 2: h2(bf16) = hbn(f32) @ W2 ; as2/ad2 (pre-scaled) ----------
__global__ __launch_bounds__(256) void k_lin2(
    const float* __restrict__ hbn, const float* __restrict__ W2,
    const float* __restrict__ atsrc, const float* __restrict__ atdst,
    uint* __restrict__ h2u, float* __restrict__ as2, float* __restrict__ ad2) {
  __shared__ float Ws[HIDD * OUTD];
  __shared__ float xs[16 * HIDD];
  __shared__ float atS[OUTD], atD[OUTD];
  int t = threadIdx.x;
  for (int i = t; i < HIDD * OUTD; i += 256) Ws[i] = W2[i];
  if (t < OUTD) { atS[t] = atsrc[t]; atD[t] = atdst[t]; }
  for (int i = t; i < 16 * HIDD; i += 256) xs[i] = hbn[blockIdx.x * 16 * HIDD + i];
  __syncthreads();
  int nl = t >> 4, tl = t & 15;
  int node = blockIdx.x * 16 + nl;
  int j0 = 2 * tl, j1 = j0 + 1;
  float a0 = 0.f, a1 = 0.f;
#pragma unroll
  for (int k = 0; k < HIDD; k++) {
    float xv = xs[nl * HIDD + k];
    a0 += xv * Ws[k * OUTD + j0];
    a1 += xv * Ws[k * OUTD + j1];
  }
  h2u[node * 16 + tl] = pack2(a0, a1);
  float ps = a0 * atS[j0] + a1 * atS[j1];
  float pd = a0 * atD[j0] + a1 * atD[j1];
#pragma unroll
  for (int off = 8; off >= 1; off >>= 1) {
    ps += __shfl_down(ps, off, 16);
    pd += __shfl_down(pd, off, 16);
  }
  if (tl == 0) { as2[node] = ps * LOG2E; ad2[node] = pd * LOG2E; }
}

// ---------- pass 1: bucket edges by dst>>8 (count, reserve, re-read & scatter) ----------
__global__ __launch_bounds__(256) void k_bin(const int* __restrict__ ei,
                                             int* __restrict__ bcur,
                                             int* __restrict__ bins) {
  __shared__ int cnt[NBUCK];
  int t = threadIdx.x;
  for (int i = t; i < NBUCK; i += 256) cnt[i] = 0;
  __syncthreads();
  int base = blockIdx.x * EPB;
  int lim = base + EPB; if (lim > ETOT) lim = ETOT;
  for (int i = base + t; i < lim; i += 256) {
    int d = (i < EE) ? ei[EE + i] : (i - EE);
    atomicAdd(&cnt[d >> BSH], 1);
  }
  __syncthreads();
  for (int i = t; i < NBUCK; i += 256) cnt[i] = atomicAdd(&bcur[i], cnt[i]);
  __syncthreads();
  for (int i = base + t; i < lim; i += 256) {
    int s, d;
    if (i < EE) { s = ei[i]; d = ei[EE + i]; } else { s = i - EE; d = s; }
    int bk = d >> BSH;
    int pos = atomicAdd(&cnt[bk], 1);
    bins[bk * CAP + pos] = (s << BSH) | (d & ((1 << BSH) - 1));
  }
}

// ---------- pass 2: per-bucket local CSR (391 blocks), inline 512-scan ----------
// srcs entries are stored PRE-SCALED by 8 (uint4/uint2 row offsets).
__global__ __launch_bounds__(256) void k_csr(const int* __restrict__ bcur,
                                             const int* __restrict__ bins,
                                             int* __restrict__ rowp,
                                             int* __restrict__ srcs) {
  __shared__ int lrec[CAP];          // 20KB
  __shared__ int sA[512], sB[512];
  __shared__ int ldeg[256];
  int b = blockIdx.x, t = threadIdx.x;
  if (b == 0 && t == 0) rowp[NN] = ETOT;
  // inline exclusive scan of the NBUCK bucket counts
  sA[t] = (t < NBUCK) ? bcur[t] : 0;
  sA[t + 256] = (t + 256 < NBUCK) ? bcur[t + 256] : 0;
  __syncthreads();
  int* in = sA; int* out = sB;
  for (int off = 1; off < 512; off <<= 1) {
    for (int i = t; i < 512; i += 256)
      out[i] = in[i] + ((i >= off) ? in[i - off] : 0);
    __syncthreads();
    int* tmp = in; in = out; out = tmp;
  }
  int gb = (b == 0) ? 0 : in[b - 1];
  __syncthreads();
  int count = bcur[b]; if (count > CAP) count = CAP;
  ldeg[t] = 0;
  __syncthreads();
  for (int i = t; i < count; i += 256) {
    int r = bins[b * CAP + i];
    lrec[i] = r;
    atomicAdd(&ldeg[r & 255], 1);
  }
  __syncthreads();
  int dv = ldeg[t];
  sA[t] = dv;
  __syncthreads();
  in = sA; out = sB;
  for (int off = 1; off < 256; off <<= 1) {
    out[t] = in[t] + ((t >= off) ? in[t - off] : 0);
    __syncthreads();
    int* tmp = in; in = out; out = tmp;
  }
  int nb = b << BSH;
  int ex = in[t] - dv;               // exclusive scan
  if (nb + t < NN) rowp[nb + t] = gb + ex;
  ldeg[t] = ex;                      // reuse as scatter cursor
  __syncthreads();
  for (int i = t; i < count; i += 256) {
    int r = lrec[i];
    int pos = atomicAdd(&ldeg[r & 255], 1);
    srcs[gb + pos] = (r >> BSH) << 3;   // pre-scaled src*8
  }
}

// ---------- GAT1 aggregation + bias + BN1 + ReLU, DUAL-node waves ----------
// srcs pre-scaled by 8; prefetch clamped to lastp (stays on a hot row).
__global__ __launch_bounds__(256, 4) void k_agg1(
    const int* __restrict__ rowp, const int* __restrict__ srcs,
    const uint* __restrict__ h1u, const float* __restrict__ as1,
    const float* __restrict__ ad1, const float* __restrict__ b1,
    const float* __restrict__ g, const float* __restrict__ bb,
    const float* __restrict__ m, const float* __restrict__ v,
    float* __restrict__ hbn) {
  int t = threadIdx.x;
  int wid = t >> 6, lane = t & 63;
  int nA = blockIdx.x * 8 + wid * 2;
  int nB = nA + 1;
  int slot = lane >> 3;
  int fl = lane & 7;
  int hd = fl >> 1;
  int stA = rowp[nA], eA = rowp[nA + 1], eB = rowp[nB + 1];
  int stB = eA;
  int lpA = eA - 1, lpB = eB - 1;     // deg >= 1 (self-loop)
  float advA = ad1[nA * NHEADS + hd];
  float advB = ad1[nB * NHEADS + hd];
  const uint4* h14 = (const uint4*)h1u;
  float accA[8] = {0,0,0,0,0,0,0,0}, accB[8] = {0,0,0,0,0,0,0,0};
  float lA = 0.f, lB = 0.f;
  int pA = stA + slot, pB = stB + slot;
  int sA0 = srcs[pA < lpA ? pA : lpA];   // pre-scaled s*8
  int sB0 = srcs[pB < lpB ? pB : lpB];
  uint4 wA = h14[sA0 + fl];
  uint4 wB = h14[sB0 + fl];
  float asA = as1[(sA0 >> 1) + hd];
  float asB = as1[(sB0 >> 1) + hd];
  int p1A = pA + 8, p1B = pB + 8;
  int sA1 = srcs[p1A < lpA ? p1A : lpA];
  int sB1 = srcs[p1B < lpB ? p1B : lpB];
  while (pA < eA || pB < eB) {
    uint4 wnA = h14[sA1 + fl];
    uint4 wnB = h14[sB1 + fl];
    float anA = as1[(sA1 >> 1) + hd];
    float anB = as1[(sB1 >> 1) + hd];
    int p2A = p1A + 8, p2B = p1B + 8;
    int sA2 = srcs[p2A < lpA ? p2A : lpA];
    int sB2 = srcs[p2B < lpB ? p2B : lpB];
    if (pA < eA) {
      float e = asA + advA;
      e = fmaxf(e, 0.2f * e);
      float ex = exp2f(e);            // as/ad pre-scaled by log2e
      lA += ex;
      accA[0] += ex * lo2f(wA.x); accA[1] += ex * hi2r(wA.x);
      accA[2] += ex * lo2f(wA.y); accA[3] += ex * hi2r(wA.y);
      accA[4] += ex * lo2f(wA.z); accA[5] += ex * hi2r(wA.z);
      accA[6] += ex * lo2f(wA.w); accA[7] += ex * hi2r(wA.w);
    }
    if (pB < eB) {
      float e = asB + advB;
      e = fmaxf(e, 0.2f * e);
      float ex = exp2f(e);
      lB += ex;
      accB[0] += ex * lo2f(wB.x); accB[1] += ex * hi2r(wB.x);
      accB[2] += ex * lo2f(wB.y); accB[3] += ex * hi2r(wB.y);
      accB[4] += ex * lo2f(wB.z); accB[5] += ex * hi2r(wB.z);
      accB[6] += ex * lo2f(wB.w); accB[7] += ex * hi2r(wB.w);
    }
    wA = wnA; wB = wnB; asA = anA; asB = anB;
    sA1 = sA2; sB1 = sB2;
    pA = p1A; pB = p1B; p1A = p2A; p1B = p2B;
  }
#pragma unroll
  for (int off = 8; off <= 32; off <<= 1) {
#pragma unroll
    for (int i = 0; i < 8; i++) {
      accA[i] += __shfl_xor(accA[i], off, 64);
      accB[i] += __shfl_xor(accB[i], off, 64);
    }
    lA += __shfl_xor(lA, off, 64);
    lB += __shfl_xor(lB, off, 64);
  }
  if (slot < 2) {
    int node = slot == 0 ? nA : nB;
    float lsum = slot == 0 ? lA : lB;
    float li = 1.f / (lsum + 1e-16f);
    int fb = fl * 8;
    float o[8];
#pragma unroll
    for (int i = 0; i < 8; i++) {
      int j = fb + i;
      float av = slot == 0 ? accA[i] : accB[i];
      float ov = av * li + b1[j];
      ov = (ov - m[j]) * rsqrtf(v[j] + 1e-5f) * g[j] + bb[j];
      o[i] = fmaxf(ov, 0.f);
    }
    float4* dst = (float4*)(hbn + node * HIDD + fb);
    dst[0] = make_float4(o[0], o[1], o[2], o[3]);
    dst[1] = make_float4(o[4], o[5], o[6], o[7]);
  }
}

// ---------- GAT2 aggregation + bias + BN2 + ReLU, DUAL-node waves ----------
__global__ __launch_bounds__(256, 4) void k_agg2(
    const int* __restrict__ rowp, const int* __restrict__ srcs,
    const uint* __restrict__ h2u, const float* __restrict__ as2,
    const float* __restrict__ ad2, const float* __restrict__ b2v,
    const float* __restrict__ g, const float* __restrict__ bb,
    const float* __restrict__ m, const float* __restrict__ v,
    float* __restrict__ out_emb) {
  int t = threadIdx.x;
  int wid = t >> 6, lane = t & 63;
  int nA = blockIdx.x * 8 + wid * 2;
  int nB = nA + 1;
  int slot = lane >> 3;
  int fl = lane & 7;         // feats fl*4..fl*4+3
  int stA = rowp[nA], eA = rowp[nA + 1], eB = rowp[nB + 1];
  int stB = eA;
  int lpA = eA - 1, lpB = eB - 1;
  float advA = ad2[nA], advB = ad2[nB];
  const uint2* h22 = (const uint2*)h2u;
  float accA[4] = {0,0,0,0}, accB[4] = {0,0,0,0};
  float lA = 0.f, lB = 0.f;
  int pA = stA + slot, pB = stB + slot;
  int sA0 = srcs[pA < lpA ? pA : lpA];   // pre-scaled s*8 (= uint2 row offset)
  int sB0 = srcs[pB < lpB ? pB : lpB];
  uint2 wA = h22[sA0 + fl];
  uint2 wB = h22[sB0 + fl];
  float asA = as2[sA0 >> 3], asB = as2[sB0 >> 3];
  int p1A = pA + 8, p1B = pB + 8;
  int sA1 = srcs[p1A < lpA ? p1A : lpA];
  int sB1 = srcs[p1B < lpB ? p1B : lpB];
  while (pA < eA || pB < eB) {
    uint2 wnA = h22[sA1 + fl];
    uint2 wnB = h22[sB1 + fl];
    float anA = as2[sA1 >> 3], anB = as2[sB1 >> 3];
    int p2A = p1A + 8, p2B = p1B + 8;
    int sA2 = srcs[p2A < lpA ? p2A : lpA];
    int sB2 = srcs[p2B < lpB ? p2B : lpB];
    if (pA < eA) {
      float e = asA + advA;
      e = fmaxf(e, 0.2f * e);
      float ex = exp2f(e);
      lA += ex;
      accA[0] += ex * lo2f(wA.x); accA[1] += ex * hi2r(wA.x);
      accA[2] += ex * lo2f(wA.y); accA[3] += ex * hi2r(wA.y);
    }
    if (pB < eB) {
      float e = asB + advB;
      e = fmaxf(e, 0.2f * e);
      float ex = exp2f(e);
      lB += ex;
      accB[0] += ex * lo2f(wB.x); accB[1] += ex * hi2r(wB.x);
      accB[2] += ex * lo2f(wB.y); accB[3] += ex * hi2r(wB.y);
    }
    wA = wnA; wB = wnB; asA = anA; asB = anB;
    sA1 = sA2; sB1 = sB2;
    pA = p1A; pB = p1B; p1A = p2A; p1B = p2B;
  }
#pragma unroll
  for (int off = 8; off <= 32; off <<= 1) {
#pragma unroll
    for (int i = 0; i < 4; i++) {
      accA[i] += __shfl_xor(accA[i], off, 64);
      accB[i] += __shfl_xor(accB[i], off, 64);
    }
    lA += __shfl_xor(lA, off, 64);
    lB += __shfl_xor(lB, off, 64);
  }
  if (slot < 2) {
    int node = slot == 0 ? nA : nB;
    float lsum = slot == 0 ? lA : lB;
    float li = 1.f / (lsum + 1e-16f);
    int fb = fl * 4;
    float o[4];
#pragma unroll
    for (int i = 0; i < 4; i++) {
      int j = fb + i;
      float av = slot == 0 ? accA[i] : accB[i];
      float ov = av * li + b2v[j];
      ov = (ov - m[j]) * rsqrtf(v[j] + 1e-5f) * g[j] + bb[j];
      o[i] = fmaxf(ov, 0.f);
    }
    *(float4*)(out_emb + node * OUTD + fb) = make_float4(o[0], o[1], o[2], o[3]);
  }
}

// ---------- classifier + regressor heads (thread per node) ----------
__global__ __launch_bounds__(256) void k_mlp(
    const float* __restrict__ embf,
    const float* __restrict__ cw1, const float* __restrict__ cb1,
    const float* __restrict__ cw2, const float* __restrict__ cb2,
    const float* __restrict__ rw1, const float* __restrict__ rb1,
    const float* __restrict__ rw2, const float* __restrict__ rb2,
    float* __restrict__ out_roles, float* __restrict__ out_energy) {
  __shared__ float C1[OUTD * HID2D], R1[OUTD * HID2D];
  __shared__ float C2[HID2D * 3], CB1[HID2D], RB1[HID2D], R2[HID2D];
  __shared__ float CB2v[3], RB2v;
  int t = threadIdx.x;
  for (int i = t; i < OUTD * HID2D; i += 256) { C1[i] = cw1[i]; R1[i] = rw1[i]; }
  if (t < HID2D) { CB1[t] = cb1[t]; RB1[t] = rb1[t]; R2[t] = rw2[t]; }
  if (t < HID2D * 3) C2[t] = cw2[t];
  if (t < 3) CB2v[t] = cb2[t];
  if (t == 0) RB2v = rb2[0];
  __syncthreads();
  int node = blockIdx.x * 256 + t;
  if (node >= NN) return;
  float e[OUTD];
#pragma unroll
  for (int k = 0; k < OUTD; k++) e[k] = embf[node * OUTD + k];
  float r0 = CB2v[0], r1 = CB2v[1], r2 = CB2v[2], en = RB2v;
  for (int j = 0; j < HID2D; j++) {
    float hc = CB1[j], hr = RB1[j];
#pragma unroll
    for (int k = 0; k < OUTD; k++) {
      hc += e[k] * C1[k * HID2D + j];
      hr += e[k] * R1[k * HID2D + j];
    }
    hc = fmaxf(hc, 0.f);
    hr = fmaxf(hr, 0.f);
    r0 += hc * C2[j * 3 + 0];
    r1 += hc * C2[j * 3 + 1];
    r2 += hc * C2[j * 3 + 2];
    en += hr * R2[j];
  }
  out_roles[node * 3 + 0] = r0;
  out_roles[node * 3 + 1] = r1;
  out_roles[node * 3 + 2] = r2;
  out_energy[node] = en;
}

extern "C" void kernel_launch(void* const* d_in, const int* in_sizes, int n_in,
                              void* d_out, int out_size, void* d_ws, size_t ws_size,
                              hipStream_t stream) {
  const float* x    = (const float*)d_in[0];
  const int*   ei   = (const int*)d_in[1];
  const float* W1   = (const float*)d_in[2];
  const float* as1w = (const float*)d_in[3];
  const float* ad1w = (const float*)d_in[4];
  const float* b1   = (const float*)d_in[5];
  const float* W2   = (const float*)d_in[6];
  const float* as2w = (const float*)d_in[7];
  const float* ad2w = (const float*)d_in[8];
  const float* b2v  = (const float*)d_in[9];
  const float* bn1g = (const float*)d_in[10];
  const float* bn1b = (const float*)d_in[11];
  const float* bn1m = (const float*)d_in[12];
  const float* bn1v = (const float*)d_in[13];
  const float* bn2g = (const float*)d_in[14];
  const float* bn2b = (const float*)d_in[15];
  const float* bn2m = (const float*)d_in[16];
  const float* bn2v = (const float*)d_in[17];
  const float* cw1  = (const float*)d_in[18];
  const float* cb1  = (const float*)d_in[19];
  const float* cw2  = (const float*)d_in[20];
  const float* cb2  = (const float*)d_in[21];
  const float* rw1  = (const float*)d_in[22];
  const float* rb1  = (const float*)d_in[23];
  const float* rw2  = (const float*)d_in[24];
  const float* rb2  = (const float*)d_in[25];

  // workspace (~56 MB), no aliasing
  uint*  h1u = (uint*)d_ws;               // N*32 uints (bf16x2) = 12.8MB
  float* hbn = (float*)(h1u + NN * 32);   // N*64 f32 = 25.6MB
  float* as1 = hbn + NN * HIDD;           // N*4
  float* ad1 = as1 + NN * NHEADS;         // N*4
  int* rowp  = (int*)(ad1 + NN * NHEADS); // N+1
  int* srcs  = rowp + NN + 1;             // ETOT
  int* bcur  = srcs + ETOT;               // 512
  int* bins  = bcur + 512;                // NBUCK*CAP = 2.0M ints (8MB)
  uint* h2u  = h1u;                       // N*16 uints fits h1u slot (h1 dead)
  float* as2 = as1;
  float* ad2 = ad1;

  float* out        = (float*)d_out;
  float* out_emb    = out;                   // N*32
  float* out_roles  = out + NN * OUTD;       // N*3
  float* out_energy = out + NN * (OUTD + 3); // N*1

  hipMemsetAsync(bcur, 0, 512 * sizeof(int), stream);
  k_lin1<<<NN / 8, 256, 0, stream>>>(x, W1, as1w, ad1w, h1u, as1, ad1);
  k_bin<<<(ETOT + EPB - 1) / EPB, 256, 0, stream>>>(ei, bcur, bins);
  k_csr<<<NBUCK, 256, 0, stream>>>(bcur, bins, rowp, srcs);
  k_agg1<<<NN / 8, 256, 0, stream>>>(rowp, srcs, h1u, as1, ad1, b1, bn1g, bn1b, bn1m, bn1v, hbn);
  k_lin2<<<NN / 16, 256, 0, stream>>>(hbn, W2, as2w, ad2w, h2u, as2, ad2);
  k_agg2<<<NN / 8, 256, 0, stream>>>(rowp, srcs, h2u, as2, ad2, b2v, bn2g, bn2b, bn2m, bn2v, out_emb);
  k_mlp<<<(NN + 255) / 256, 256, 0, stream>>>(out_emb, cw1, cb1, cw2, cb2, rw1, rb1, rw2, rb2, out_roles, out_energy);
}

// Round 16
// 315.186 us; speedup vs baseline: 1.0486x; 1.0124x over previous
//
#include <hip/hip_runtime.h>
#include <hip/hip_bf16.h>

#define NN 100000
#define EE 1600000
#define ETOT (EE + NN)          // 1,700,000 edges incl. self-loops
#define IND 32
#define HIDD 64
#define NHEADS 4
#define OUTD 32
#define HID2D 32
#define LOG2E 1.44269504f

#define BSH 8                   // 256 nodes per bucket
#define NBUCK 391               // ceil(NN / 256)
#define CAP 5120                // max edges per bucket (mean ~4348)
#define EPB 8192                // edges per bin block (count + rescatter)

typedef unsigned int uint;

__device__ __forceinline__ uint pack2(float a, float b) {
  uint lo = (uint)__bfloat16_as_ushort(__float2bfloat16(a));
  uint hi = (uint)__bfloat16_as_ushort(__float2bfloat16(b));
  return (hi << 16) | lo;
}
__device__ __forceinline__ float lo2f(uint w) { return __uint_as_float(w << 16); }
// raw reinterpret: low 16 bits act as <=1-ulp mantissa noise (saves the AND)
__device__ __forceinline__ float hi2r(uint w) { return __uint_as_float(w); }

// ---------- linear 1: h1(bf16) = x @ W1 ; as1/ad1 (pre-scaled by log2e) ----------
// block 0 also zeroes bcur (replaces the memset dispatch; k_bin runs after).
__global__ __launch_bounds__(256) void k_lin1(
    const float* __restrict__ x, const float* __restrict__ W1,
    const float* __restrict__ atsrc, const float* __restrict__ atdst,
    uint* __restrict__ h1u, float* __restrict__ as1, float* __restrict__ ad1,
    int* __restrict__ bcur) {
  __shared__ float Ws[IND * HIDD];
  __shared__ float xs[8 * IND];
  __shared__ float atS[HIDD], atD[HIDD];
  int t = threadIdx.x;
  if (blockIdx.x == 0) { bcur[t] = 0; bcur[t + 256] = 0; }
  for (int i = t; i < IND * HIDD; i += 256) Ws[i] = W1[i];
  if (t < HIDD) { atS[t] = atsrc[t]; atD[t] = atdst[t]; }
  xs[t] = x[blockIdx.x * 256 + t];
  __syncthreads();
  int nl = t >> 5, tl = t & 31;
  int node = blockIdx.x * 8 + nl;
  int j0 = 2 * tl, j1 = j0 + 1;
  float a0 = 0.f, a1 = 0.f;
#pragma unroll
  for (int k = 0; k < IND; k++) {
    float xv = xs[nl * IND + k];
    a0 += xv * Ws[k * HIDD + j0];
    a1 += xv * Ws[k * HIDD + j1];
  }
  h1u[node * 32 + tl] = pack2(a0, a1);
  float ps = a0 * atS[j0] + a1 * atS[j1];
  float pd = a0 * atD[j0] + a1 * atD[j1];
#pragma unroll
  for (int off = 4; off >= 1; off >>= 1) {
    ps += __shfl_down(ps, off, 8);
    pd += __shfl_down(pd, off, 8);
  }
  if ((tl & 7) == 0) {
    as1[node * NHEADS + (tl >> 3)] = ps * LOG2E;
    ad1[node * NHEADS + (tl >> 3)] = pd * LOG2E;
  }
}

// ---------- linear 2: h2(bf16) = hbn(f32) @ W2 ; as2/ad2 (pre-scaled) ----------
__global__ __launch_bounds__(256) void k_lin2(
    const float* __restrict__ hbn, const float* __restrict__ W2,
    const float* __restrict__ atsrc, const float* __restrict__ atdst,
    uint* __restrict__ h2u, float* __restrict__ as2, float* __restrict__ ad2) {
  __shared__ float Ws[HIDD * OUTD];
  __shared__ float xs[16 * HIDD];
  __shared__ float atS[OUTD], atD[OUTD];
  int t = threadIdx.x;
  for (int i = t; i < HIDD * OUTD; i += 256) Ws[i] = W2[i];
  if (t < OUTD) { atS[t] = atsrc[t]; atD[t] = atdst[t]; }
  for (int i = t; i < 16 * HIDD; i += 256) xs[i] = hbn[blockIdx.x * 16 * HIDD + i];
  __syncthreads();
  int nl = t >> 4, tl = t & 15;
  int node = blockIdx.x * 16 + nl;
  int j0 = 2 * tl, j1 = j0 + 1;
  float a0 = 0.f, a1 = 0.f;
#pragma unroll
  for (int k = 0; k < HIDD; k++) {
    float xv = xs[nl * HIDD + k];
    a0 += xv * Ws[k * OUTD + j0];
    a1 += xv * Ws[k * OUTD + j1];
  }
  h2u[node * 16 + tl] = pack2(a0, a1);
  float ps = a0 * atS[j0] + a1 * atS[j1];
  float pd = a0 * atD[j0] + a1 * atD[j1];
#pragma unroll
  for (int off = 8; off >= 1; off >>= 1) {
    ps += __shfl_down(ps, off, 16);
    pd += __shfl_down(pd, off, 16);
  }
  if (tl == 0) { as2[node] = ps * LOG2E; ad2[node] = pd * LOG2E; }
}

// ---------- pass 1: bucket edges by dst>>8 (count, reserve, re-read & scatter) ----------
__global__ __launch_bounds__(256) void k_bin(const int* __restrict__ ei,
                                             int* __restrict__ bcur,
                                             int* __restrict__ bins) {
  __shared__ int cnt[NBUCK];
  int t = threadIdx.x;
  for (int i = t; i < NBUCK; i += 256) cnt[i] = 0;
  __syncthreads();
  int base = blockIdx.x * EPB;
  int lim = base + EPB; if (lim > ETOT) lim = ETOT;
  for (int i = base + t; i < lim; i += 256) {
    int d = (i < EE) ? ei[EE + i] : (i - EE);
    atomicAdd(&cnt[d >> BSH], 1);
  }
  __syncthreads();
  for (int i = t; i < NBUCK; i += 256) cnt[i] = atomicAdd(&bcur[i], cnt[i]);
  __syncthreads();
  for (int i = base + t; i < lim; i += 256) {
    int s, d;
    if (i < EE) { s = ei[i]; d = ei[EE + i]; } else { s = i - EE; d = s; }
    int bk = d >> BSH;
    int pos = atomicAdd(&cnt[bk], 1);
    bins[bk * CAP + pos] = (s << BSH) | (d & ((1 << BSH) - 1));
  }
}

// ---------- pass 2: per-bucket local CSR (391 blocks), inline 512-scan ----------
// srcs entries are stored PRE-SCALED by 8 (uint4/uint2 row offsets).
__global__ __launch_bounds__(256) void k_csr(const int* __restrict__ bcur,
                                             const int* __restrict__ bins,
                                             int* __restrict__ rowp,
                                             int* __restrict__ srcs) {
  __shared__ int lrec[CAP];          // 20KB
  __shared__ int sA[512], sB[512];
  __shared__ int ldeg[256];
  int b = blockIdx.x, t = threadIdx.x;
  if (b == 0 && t == 0) rowp[NN] = ETOT;
  sA[t] = (t < NBUCK) ? bcur[t] : 0;
  sA[t + 256] = (t + 256 < NBUCK) ? bcur[t + 256] : 0;
  __syncthreads();
  int* in = sA; int* out = sB;
  for (int off = 1; off < 512; off <<= 1) {
    for (int i = t; i < 512; i += 256)
      out[i] = in[i] + ((i >= off) ? in[i - off] : 0);
    __syncthreads();
    int* tmp = in; in = out; out = tmp;
  }
  int gb = (b == 0) ? 0 : in[b - 1];
  __syncthreads();
  int count = bcur[b]; if (count > CAP) count = CAP;
  ldeg[t] = 0;
  __syncthreads();
  for (int i = t; i < count; i += 256) {
    int r = bins[b * CAP + i];
    lrec[i] = r;
    atomicAdd(&ldeg[r & 255], 1);
  }
  __syncthreads();
  int dv = ldeg[t];
  sA[t] = dv;
  __syncthreads();
  in = sA; out = sB;
  for (int off = 1; off < 256; off <<= 1) {
    out[t] = in[t] + ((t >= off) ? in[t - off] : 0);
    __syncthreads();
    int* tmp = in; in = out; out = tmp;
  }
  int nb = b << BSH;
  int ex = in[t] - dv;               // exclusive scan
  if (nb + t < NN) rowp[nb + t] = gb + ex;
  ldeg[t] = ex;                      // reuse as scatter cursor
  __syncthreads();
  for (int i = t; i < count; i += 256) {
    int r = lrec[i];
    int pos = atomicAdd(&ldeg[r & 255], 1);
    srcs[gb + pos] = (r >> BSH) << 3;   // pre-scaled src*8
  }
}

// ---------- GAT1 aggregation + bias + BN1 + ReLU, QUAD-node waves ----------
// 4 independent gather pipelines per wave; clamped depth-2 prefetch.
__global__ __launch_bounds__(256, 4) void k_agg1(
    const int* __restrict__ rowp, const int* __restrict__ srcs,
    const uint* __restrict__ h1u, const float* __restrict__ as1,
    const float* __restrict__ ad1, const float* __restrict__ b1,
    const float* __restrict__ g, const float* __restrict__ bb,
    const float* __restrict__ m, const float* __restrict__ v,
    float* __restrict__ hbn) {
  int t = threadIdx.x;
  int wid = t >> 6, lane = t & 63;
  int n0 = blockIdx.x * 16 + wid * 4;
  int slot = lane >> 3;
  int fl = lane & 7;
  int hd = fl >> 1;
  int rp[5];
#pragma unroll
  for (int k = 0; k < 5; k++) rp[k] = rowp[n0 + k];
  const uint4* h14 = (const uint4*)h1u;
  float acc[4][8], l[4], adv[4], as[4];
  int p[4], p1[4], lp[4], en[4], s1v[4];
  uint4 w[4];
#pragma unroll
  for (int k = 0; k < 4; k++) {
    adv[k] = ad1[(n0 + k) * NHEADS + hd];
    en[k] = rp[k + 1];
    lp[k] = en[k] - 1;                 // deg >= 1 (self-loop)
    p[k] = rp[k] + slot;
    int pc = p[k] < lp[k] ? p[k] : lp[k];
    int s0 = srcs[pc];                 // pre-scaled s*8
    w[k] = h14[s0 + fl];
    as[k] = as1[(s0 >> 1) + hd];
    p1[k] = p[k] + 8;
    int pc1 = p1[k] < lp[k] ? p1[k] : lp[k];
    s1v[k] = srcs[pc1];
    l[k] = 0.f;
#pragma unroll
    for (int i = 0; i < 8; i++) acc[k][i] = 0.f;
  }
  while (p[0] < en[0] || p[1] < en[1] || p[2] < en[2] || p[3] < en[3]) {
    uint4 wn[4]; float an[4]; int s2[4];
#pragma unroll
    for (int k = 0; k < 4; k++) {
      wn[k] = h14[s1v[k] + fl];
      an[k] = as1[(s1v[k] >> 1) + hd];
      int p2 = p1[k] + 8;
      int pc = p2 < lp[k] ? p2 : lp[k];
      s2[k] = srcs[pc];
    }
#pragma unroll
    for (int k = 0; k < 4; k++) {
      if (p[k] < en[k]) {
        float e = as[k] + adv[k];
        e = fmaxf(e, 0.2f * e);
        float ex = exp2f(e);           // as/ad pre-scaled by log2e
        l[k] += ex;
        acc[k][0] += ex * lo2f(w[k].x); acc[k][1] += ex * hi2r(w[k].x);
        acc[k][2] += ex * lo2f(w[k].y); acc[k][3] += ex * hi2r(w[k].y);
        acc[k][4] += ex * lo2f(w[k].z); acc[k][5] += ex * hi2r(w[k].z);
        acc[k][6] += ex * lo2f(w[k].w); acc[k][7] += ex * hi2r(w[k].w);
      }
      w[k] = wn[k]; as[k] = an[k]; s1v[k] = s2[k];
      p[k] = p1[k]; p1[k] += 8;
    }
  }
#pragma unroll
  for (int off = 8; off <= 32; off <<= 1) {
#pragma unroll
    for (int k = 0; k < 4; k++) {
#pragma unroll
      for (int i = 0; i < 8; i++) acc[k][i] += __shfl_xor(acc[k][i], off, 64);
      l[k] += __shfl_xor(l[k], off, 64);
    }
  }
  if (slot < 4) {
    float lsum = 0.f, av[8];
#pragma unroll
    for (int i = 0; i < 8; i++) av[i] = 0.f;
#pragma unroll
    for (int k = 0; k < 4; k++) {
      if (slot == k) {
        lsum = l[k];
#pragma unroll
        for (int i = 0; i < 8; i++) av[i] = acc[k][i];
      }
    }
    int node = n0 + slot;
    float li = 1.f / (lsum + 1e-16f);
    int fb = fl * 8;
    float o[8];
#pragma unroll
    for (int i = 0; i < 8; i++) {
      int j = fb + i;
      float ov = av[i] * li + b1[j];
      ov = (ov - m[j]) * rsqrtf(v[j] + 1e-5f) * g[j] + bb[j];
      o[i] = fmaxf(ov, 0.f);
    }
    float4* dst = (float4*)(hbn + node * HIDD + fb);
    dst[0] = make_float4(o[0], o[1], o[2], o[3]);
    dst[1] = make_float4(o[4], o[5], o[6], o[7]);
  }
}

// ---------- GAT2 aggregation + bias + BN2 + ReLU, QUAD-node waves ----------
__global__ __launch_bounds__(256, 4) void k_agg2(
    const int* __restrict__ rowp, const int* __restrict__ srcs,
    const uint* __restrict__ h2u, const float* __restrict__ as2,
    const float* __restrict__ ad2, const float* __restrict__ b2v,
    const float* __restrict__ g, const float* __restrict__ bb,
    const float* __restrict__ m, const float* __restrict__ v,
    float* __restrict__ out_emb) {
  int t = threadIdx.x;
  int wid = t >> 6, lane = t & 63;
  int n0 = blockIdx.x * 16 + wid * 4;
  int slot = lane >> 3;
  int fl = lane & 7;                   // feats fl*4..fl*4+3
  int rp[5];
#pragma unroll
  for (int k = 0; k < 5; k++) rp[k] = rowp[n0 + k];
  const uint2* h22 = (const uint2*)h2u;
  float acc[4][4], l[4], adv[4], as[4];
  int p[4], p1[4], lp[4], en[4], s1v[4];
  uint2 w[4];
#pragma unroll
  for (int k = 0; k < 4; k++) {
    adv[k] = ad2[n0 + k];
    en[k] = rp[k + 1];
    lp[k] = en[k] - 1;
    p[k] = rp[k] + slot;
    int pc = p[k] < lp[k] ? p[k] : lp[k];
    int s0 = srcs[pc];                 // pre-scaled s*8 (= uint2 row offset)
    w[k] = h22[s0 + fl];
    as[k] = as2[s0 >> 3];
    p1[k] = p[k] + 8;
    int pc1 = p1[k] < lp[k] ? p1[k] : lp[k];
    s1v[k] = srcs[pc1];
    l[k] = 0.f;
#pragma unroll
    for (int i = 0; i < 4; i++) acc[k][i] = 0.f;
  }
  while (p[0] < en[0] || p[1] < en[1] || p[2] < en[2] || p[3] < en[3]) {
    uint2 wn[4]; float an[4]; int s2[4];
#pragma unroll
    for (int k = 0; k < 4; k++) {
      wn[k] = h22[s1v[k] + fl];
      an[k] = as2[s1v[k] >> 3];
      int p2 = p1[k] + 8;
      int pc = p2 < lp[k] ? p2 : lp[k];
      s2[k] = srcs[pc];
    }
#pragma unroll
    for (int k = 0; k < 4; k++) {
      if (p[k] < en[k]) {
        float e = as[k] + adv[k];
        e = fmaxf(e, 0.2f * e);
        float ex = exp2f(e);
        l[k] += ex;
        acc[k][0] += ex * lo2f(w[k].x); acc[k][1] += ex * hi2r(w[k].x);
        acc[k][2] += ex * lo2f(w[k].y); acc[k][3] += ex * hi2r(w[k].y);
      }
      w[k] = wn[k]; as[k] = an[k]; s1v[k] = s2[k];
      p[k] = p1[k]; p1[k] += 8;
    }
  }
#pragma unroll
  for (int off = 8; off <= 32; off <<= 1) {
#pragma unroll
    for (int k = 0; k < 4; k++) {
#pragma unroll
      for (int i = 0; i < 4; i++) acc[k][i] += __shfl_xor(acc[k][i], off, 64);
      l[k] += __shfl_xor(l[k], off, 64);
    }
  }
  if (slot < 4) {
    float lsum = 0.f, av[4];
#pragma unroll
    for (int i = 0; i < 4; i++) av[i] = 0.f;
#pragma unroll
    for (int k = 0; k < 4; k++) {
      if (slot == k) {
        lsum = l[k];
#pragma unroll
        for (int i = 0; i < 4; i++) av[i] = acc[k][i];
      }
    }
    int node = n0 + slot;
    float li = 1.f / (lsum + 1e-16f);
    int fb = fl * 4;
    float o[4];
#pragma unroll
    for (int i = 0; i < 4; i++) {
      int j = fb + i;
      float ov = av[i] * li + b2v[j];
      ov = (ov - m[j]) * rsqrtf(v[j] + 1e-5f) * g[j] + bb[j];
      o[i] = fmaxf(ov, 0.f);
    }
    *(float4*)(out_emb + node * OUTD + fb) = make_float4(o[0], o[1], o[2], o[3]);
  }
}

// ---------- classifier + regressor heads (thread per node) ----------
__global__ __launch_bounds__(256) void k_mlp(
    const float* __restrict__ embf,
    const float* __restrict__ cw1, const float* __restrict__ cb1,
    const float* __restrict__ cw2, const float* __restrict__ cb2,
    const float* __restrict__ rw1, const float* __restrict__ rb1,
    const float* __restrict__ rw2, const float* __restrict__ rb2,
    float* __restrict__ out_roles, float* __restrict__ out_energy) {
  __shared__ float C1[OUTD * HID2D], R1[OUTD * HID2D];
  __shared__ float C2[HID2D * 3], CB1[HID2D], RB1[HID2D], R2[HID2D];
  __shared__ float CB2v[3], RB2v;
  int t = threadIdx.x;
  for (int i = t; i < OUTD * HID2D; i += 256) { C1[i] = cw1[i]; R1[i] = rw1[i]; }
  if (t < HID2D) { CB1[t] = cb1[t]; RB1[t] = rb1[t]; R2[t] = rw2[t]; }
  if (t < HID2D * 3) C2[t] = cw2[t];
  if (t < 3) CB2v[t] = cb2[t];
  if (t == 0) RB2v = rb2[0];
  __syncthreads();
  int node = blockIdx.x * 256 + t;
  if (node >= NN) return;
  float e[OUTD];
#pragma unroll
  for (int k = 0; k < OUTD; k++) e[k] = embf[node * OUTD + k];
  float r0 = CB2v[0], r1 = CB2v[1], r2 = CB2v[2], en = RB2v;
  for (int j = 0; j < HID2D; j++) {
    float hc = CB1[j], hr = RB1[j];
#pragma unroll
    for (int k = 0; k < OUTD; k++) {
      hc += e[k] * C1[k * HID2D + j];
      hr += e[k] * R1[k * HID2D + j];
    }
    hc = fmaxf(hc, 0.f);
    hr = fmaxf(hr, 0.f);
    r0 += hc * C2[j * 3 + 0];
    r1 += hc * C2[j * 3 + 1];
    r2 += hc * C2[j * 3 + 2];
    en += hr * R2[j];
  }
  out_roles[node * 3 + 0] = r0;
  out_roles[node * 3 + 1] = r1;
  out_roles[node * 3 + 2] = r2;
  out_energy[node] = en;
}

extern "C" void kernel_launch(void* const* d_in, const int* in_sizes, int n_in,
                              void* d_out, int out_size, void* d_ws, size_t ws_size,
                              hipStream_t stream) {
  const float* x    = (const float*)d_in[0];
  const int*   ei   = (const int*)d_in[1];
  const float* W1   = (const float*)d_in[2];
  const float* as1w = (const float*)d_in[3];
  const float* ad1w = (const float*)d_in[4];
  const float* b1   = (const float*)d_in[5];
  const float* W2   = (const float*)d_in[6];
  const float* as2w = (const float*)d_in[7];
  const float* ad2w = (const float*)d_in[8];
  const float* b2v  = (const float*)d_in[9];
  const float* bn1g = (const float*)d_in[10];
  const float* bn1b = (const float*)d_in[11];
  const float* bn1m = (const float*)d_in[12];
  const float* bn1v = (const float*)d_in[13];
  const float* bn2g = (const float*)d_in[14];
  const float* bn2b = (const float*)d_in[15];
  const float* bn2m = (const float*)d_in[16];
  const float* bn2v = (const float*)d_in[17];
  const float* cw1  = (const float*)d_in[18];
  const float* cb1  = (const float*)d_in[19];
  const float* cw2  = (const float*)d_in[20];
  const float* cb2  = (const float*)d_in[21];
  const float* rw1  = (const float*)d_in[22];
  const float* rb1  = (const float*)d_in[23];
  const float* rw2  = (const float*)d_in[24];
  const float* rb2  = (const float*)d_in[25];

  // workspace (~56 MB), no aliasing
  uint*  h1u = (uint*)d_ws;               // N*32 uints (bf16x2) = 12.8MB
  float* hbn = (float*)(h1u + NN * 32);   // N*64 f32 = 25.6MB
  float* as1 = hbn + NN * HIDD;           // N*4
  float* ad1 = as1 + NN * NHEADS;         // N*4
  int* rowp  = (int*)(ad1 + NN * NHEADS); // N+1
  int* srcs  = rowp + NN + 1;             // ETOT
  int* bcur  = srcs + ETOT;               // 512
  int* bins  = bcur + 512;                // NBUCK*CAP = 2.0M ints (8MB)
  uint* h2u  = h1u;                       // N*16 uints fits h1u slot (h1 dead)
  float* as2 = as1;
  float* ad2 = ad1;

  float* out        = (float*)d_out;
  float* out_emb    = out;                   // N*32
  float* out_roles  = out + NN * OUTD;       // N*3
  float* out_energy = out + NN * (OUTD + 3); // N*1

  k_lin1<<<NN / 8, 256, 0, stream>>>(x, W1, as1w, ad1w, h1u, as1, ad1, bcur);
  k_bin<<<(ETOT + EPB - 1) / EPB, 256, 0, stream>>>(ei, bcur, bins);
  k_csr<<<NBUCK, 256, 0, stream>>>(bcur, bins, rowp, srcs);
  k_agg1<<<NN / 16, 256, 0, stream>>>(rowp, srcs, h1u, as1, ad1, b1, bn1g, bn1b, bn1m, bn1v, hbn);
  k_lin2<<<NN / 16, 256, 0, stream>>>(hbn, W2, as2w, ad2w, h2u, as2, ad2);
  k_agg2<<<NN / 16, 256, 0, stream>>>(rowp, srcs, h2u, as2, ad2, b2v, bn2g, bn2b, bn2m, bn2v, out_emb);
  k_mlp<<<(NN + 255) / 256, 256, 0, stream>>>(out_emb, cw1, cb1, cw2, cb2, rw1, rb1, rw2, rb2, out_roles, out_energy);
}